// Round 4
// baseline (190.976 us; speedup 1.0000x reference)
//
#include <hip/hip_runtime.h>
#include <math.h>

#define LOG2E 1.44269504088896340736f

typedef __attribute__((ext_vector_type(8))) short bfrag;   // 8 x bf16
typedef __attribute__((ext_vector_type(4))) float f4;
typedef unsigned __attribute__((ext_vector_type(2))) u2;
typedef unsigned __attribute__((ext_vector_type(4))) u4;

// ---------- helpers ----------
__device__ __forceinline__ unsigned pk_trunc(float a, float b) {
    return (__float_as_uint(a) >> 16) | (__float_as_uint(b) & 0xFFFF0000u);
}
__device__ __forceinline__ unsigned pk_rne(float a, float b) {
    unsigned ua = __float_as_uint(a); ua += 0x7FFFu + ((ua >> 16) & 1u);
    unsigned ub = __float_as_uint(b); ub += 0x7FFFu + ((ub >> 16) & 1u);
    return (ua >> 16) | (ub & 0xFFFF0000u);
}
__device__ __forceinline__ float fexp2(float x) {
#if __has_builtin(__builtin_amdgcn_exp2f)
    return __builtin_amdgcn_exp2f(x);
#else
    return exp2f(x);
#endif
}
// exchange: a's odd 16-lane rows <-> b's even 16-lane rows (VALU pipe on gfx950)
__device__ __forceinline__ void plswap16(float& a, float& b) {
#if __has_builtin(__builtin_amdgcn_permlane16_swap)
    u2 t = __builtin_amdgcn_permlane16_swap(__float_as_uint(a), __float_as_uint(b),
                                            false, false);
    a = __uint_as_float(t.x); b = __uint_as_float(t.y);
#else
    bool odd = (threadIdx.x >> 4) & 1;
    float bs = __shfl_xor(b, 16, 64);
    float as = __shfl_xor(a, 16, 64);
    float na = odd ? bs : a;
    float nb = odd ? b : as;
    a = na; b = nb;
#endif
}
// async global->LDS, 16B/lane; lds base wave-uniform, HW lands lane i at base+i*16
__device__ __forceinline__ void stage16(void* lds_base, const void* g) {
#if __has_builtin(__builtin_amdgcn_global_load_lds)
    __builtin_amdgcn_global_load_lds(
        (const __attribute__((address_space(1))) unsigned int*)g,
        (__attribute__((address_space(3))) unsigned int*)lds_base, 16, 0, 0);
#else
    int lane = threadIdx.x & 63;
    *(float4*)((char*)lds_base + lane * 16) = *(const float4*)g;
#endif
}
__device__ __forceinline__ f4 mfma_bf16(bfrag a, bfrag b, f4 c) {
    return __builtin_amdgcn_mfma_f32_16x16x32_bf16(a, b, c, 0, 0, 0);
}

// ---------- workspace byte offsets ----------
// qbuf: [bh][128 panels][hi 1KB | lo 1KB]        = 32*128*2048   = 8,388,608
// kv:   [bh][32 chunks][khi 4K|klo 4K|vt 2K]     = 32*32*10240   = 10,485,760
// x:    [B][S][128] fp32                          = 4,194,304
#define WS_QB 0u
#define WS_KV 8388608u
#define WS_X  18874368u

// ---------- fused projections ----------
// Block: 320 threads = 5 waves, 16 rows. Wave p: 0 q(W0), 1 k(W1), 2 v(W2),
// 3 pos_q(W0), 4 pos_k(W1). Lane: cg=lane&31 (4 cols), rh=lane>>5 (8 rows).
// Outputs written in MFMA fragment order (see k_attn layout contract).
__global__ __launch_bounds__(320) void k_proj(
    const float* __restrict__ q_in, const float* __restrict__ k_in,
    const float* __restrict__ v_in, const float* __restrict__ p_in,
    const float* __restrict__ W0, const float* __restrict__ W1,
    const float* __restrict__ W2,
    const float* __restrict__ b0, const float* __restrict__ b1,
    const float* __restrict__ b2,
    char* __restrict__ qb, char* __restrict__ kv)
{
    __shared__ float xs[4][16][128];   // 32 KB
    const int tid = threadIdx.x;
    const int row0 = blockIdx.x * 16;
    for (int idx = tid; idx < 2048; idx += 320) {
        int t = idx >> 9, rem = idx & 511;
        int r = rem >> 5, c4 = rem & 31;
        const float* sp = (t == 0) ? q_in : (t == 1) ? k_in : (t == 2) ? v_in : p_in;
        *(f4*)&xs[t][r][c4 * 4] = *(const f4*)(sp + (size_t)(row0 + r) * 128 + c4 * 4);
    }
    __syncthreads();

    const int p = tid >> 6;                 // wave-uniform projection id
    const int lane = tid & 63;
    const int cg = lane & 31, rh = lane >> 5;
    const int tsel = (p < 3) ? p : 3;
    const int wsel = (p == 0 || p == 3) ? 0 : (p == 1 || p == 4) ? 1 : 2;
    const float* W = (wsel == 0) ? W0 : (wsel == 1) ? W1 : W2;   // row-major [c][d]
    const float* bb_ = (wsel == 0) ? b0 : (wsel == 1) ? b1 : b2;

    float acc[8][4];
#pragma unroll
    for (int cc = 0; cc < 4; ++cc) {
        float bias = bb_[cg * 4 + cc];
#pragma unroll
        for (int i = 0; i < 8; ++i) acc[i][cc] = bias;
    }

    const float* xbase = &xs[tsel][rh * 8][0];
    const float* wbase = W + (size_t)(cg * 4) * 128;
#pragma unroll 4
    for (int dq = 0; dq < 32; ++dq) {
        f4 w0 = *(const f4*)(wbase + dq * 4);
        f4 w1 = *(const f4*)(wbase + 128 + dq * 4);
        f4 w2 = *(const f4*)(wbase + 256 + dq * 4);
        f4 w3 = *(const f4*)(wbase + 384 + dq * 4);
#pragma unroll
        for (int i = 0; i < 8; ++i) {
            f4 xr = *(const f4*)(xbase + i * 128 + dq * 4);
            acc[i][0] = fmaf(xr.x, w0.x, acc[i][0]); acc[i][0] = fmaf(xr.y, w0.y, acc[i][0]);
            acc[i][0] = fmaf(xr.z, w0.z, acc[i][0]); acc[i][0] = fmaf(xr.w, w0.w, acc[i][0]);
            acc[i][1] = fmaf(xr.x, w1.x, acc[i][1]); acc[i][1] = fmaf(xr.y, w1.y, acc[i][1]);
            acc[i][1] = fmaf(xr.z, w1.z, acc[i][1]); acc[i][1] = fmaf(xr.w, w1.w, acc[i][1]);
            acc[i][2] = fmaf(xr.x, w2.x, acc[i][2]); acc[i][2] = fmaf(xr.y, w2.y, acc[i][2]);
            acc[i][2] = fmaf(xr.z, w2.z, acc[i][2]); acc[i][2] = fmaf(xr.w, w2.w, acc[i][2]);
            acc[i][3] = fmaf(xr.x, w3.x, acc[i][3]); acc[i][3] = fmaf(xr.y, w3.y, acc[i][3]);
            acc[i][3] = fmaf(xr.z, w3.z, acc[i][3]); acc[i][3] = fmaf(xr.w, w3.w, acc[i][3]);
        }
    }

    const int bbk = row0 >> 11, ss = row0 & 2047;
    const int panel = ss >> 4, chunk = ss >> 6, pic = (ss >> 4) & 3, sub = (ss >> 5) & 1;

    if (p == 2) {
        // V: RNE bf16, key-permuted fragment order (kk-row map {0,2,1,3})
        int kkb = (ss & 31) + rh * 8;
        int m = (0x3120 >> ((kkb >> 3) * 4)) & 0xF;
#pragma unroll
        for (int cc = 0; cc < 4; ++cc) {
            int d = (cg & 3) * 4 + cc;
            int h = cg >> 2;
            size_t base = (size_t)(bbk * 8 + h) * 327680 + (size_t)chunk * 10240
                        + 8192 + sub * 1024 + (size_t)((m * 16 + d) * 8) * 2;
            u4 pkd;
            pkd.x = pk_rne(acc[0][cc], acc[1][cc]);
            pkd.y = pk_rne(acc[2][cc], acc[3][cc]);
            pkd.z = pk_rne(acc[4][cc], acc[5][cc]);
            pkd.w = pk_rne(acc[6][cc], acc[7][cc]);
            *(u4*)(kv + base) = pkd;
        }
    } else {
        const float scale = (p == 0) ? 0.25f * LOG2E : (p == 3) ? LOG2E : 1.0f;
        const int dbase = ((p == 0 || p == 1) ? 0 : 16) + (cg & 3) * 4;
        const int h = cg >> 2;
        const int fl = (dbase >> 3) * 16;      // fragment lane row-part
        const int jb = dbase & 7;              // 0 or 4
        char* dst;
        size_t hibase, lodelta;
        if (p == 0 || p == 3) {
            dst = qb;
            hibase = (size_t)(bbk * 8 + h) * 262144 + (size_t)panel * 2048;
            lodelta = 1024;
        } else {
            dst = kv;
            hibase = (size_t)(bbk * 8 + h) * 327680 + (size_t)chunk * 10240
                   + (size_t)pic * 1024;
            lodelta = 4096;
        }
#pragma unroll
        for (int i = 0; i < 8; ++i) {
            int kc = rh * 8 + i;
            size_t off = (size_t)((fl + kc) * 16 + jb * 2);
            float v0 = acc[i][0] * scale, v1 = acc[i][1] * scale;
            float v2 = acc[i][2] * scale, v3 = acc[i][3] * scale;
            float h0 = __uint_as_float(__float_as_uint(v0) & 0xFFFF0000u);
            float h1 = __uint_as_float(__float_as_uint(v1) & 0xFFFF0000u);
            float h2 = __uint_as_float(__float_as_uint(v2) & 0xFFFF0000u);
            float h3 = __uint_as_float(__float_as_uint(v3) & 0xFFFF0000u);
            u2 hiw, low;
            hiw.x = pk_trunc(v0, v1); hiw.y = pk_trunc(v2, v3);
            low.x = pk_trunc(v0 - h0, v1 - h1); low.y = pk_trunc(v2 - h2, v3 - h3);
            *(u2*)(dst + hibase + off) = hiw;
            *(u2*)(dst + hibase + lodelta + off) = low;
        }
    }
}

// ---------- fused flash attention ----------
// Block = 4 waves x 32 q-rows = 128 rows; grid (16, 32 bh). Per 64-key chunk:
// stage 10KB [khi 4K|klo 4K|vt 2K] (double-buffered); S^T = k'(A) x q'(B),
// 3 MFMAs/panel (hi/lo); exp2; C->A via permlane16_swap (key-permuted, matches
// vt packing); PV 1 MFMA/sub. No online max (scores bounded: |log2 s| < 64).
// NOTE: explicit vmcnt(0) drain before the barrier — global_load_lds's only
// consumer is other waves post-barrier; do not rely on the compiler modeling
// that dependency in this CFG (suspected cause of R3's replay-only failures).
__global__ __launch_bounds__(256) void k_attn(
    const char* __restrict__ qb, const char* __restrict__ kvg,
    float* __restrict__ xout)
{
    __shared__ __align__(16) char kbuf[2][10240];
    const int tid = threadIdx.x;
    const int w = tid >> 6, lane = tid & 63;
    const int c = lane & 15, qd = lane >> 4;
    const int bh = blockIdx.y;
    const int q0 = blockIdx.x * 128 + w * 32;

    const char* qpb = qb + (size_t)bh * 262144 + (size_t)(q0 >> 4) * 2048;
    bfrag qh0 = *(const bfrag*)(qpb + lane * 16);
    bfrag ql0 = *(const bfrag*)(qpb + 1024 + lane * 16);
    bfrag qh1 = *(const bfrag*)(qpb + 2048 + lane * 16);
    bfrag ql1 = *(const bfrag*)(qpb + 3072 + lane * 16);

    const char* kvb = kvg + (size_t)bh * 327680;

    f4 o0 = {0.f, 0.f, 0.f, 0.f}, o1 = {0.f, 0.f, 0.f, 0.f};
    float ls0 = 0.f, ls1 = 0.f;

    auto stage = [&](char* db, const char* gsrc) {
        stage16(db + w * 1024, gsrc + w * 1024 + lane * 16);
        stage16(db + (w + 4) * 1024, gsrc + (w + 4) * 1024 + lane * 16);
        if (w < 2)
            stage16(db + (8 + w) * 1024, gsrc + (8 + w) * 1024 + lane * 16);
    };

    stage(kbuf[0], kvb);
    int cur = 0;
    for (int ch = 0; ch < 32; ++ch) {
        // Force-drain this wave's outstanding global_load_lds before the
        // barrier so chunk ch's staged data is LDS-visible to all waves.
        asm volatile("s_waitcnt vmcnt(0)" ::: "memory");
        __syncthreads();
        if (ch < 31) stage(kbuf[cur ^ 1], kvb + (size_t)(ch + 1) * 10240);
        const char* kb = kbuf[cur];
#pragma unroll
        for (int sub = 0; sub < 2; ++sub) {
            bfrag ka = *(const bfrag*)(kb + (2 * sub) * 1024 + lane * 16);
            bfrag kc2 = *(const bfrag*)(kb + (2 * sub + 1) * 1024 + lane * 16);
            bfrag la = *(const bfrag*)(kb + 4096 + (2 * sub) * 1024 + lane * 16);
            bfrag lb = *(const bfrag*)(kb + 4096 + (2 * sub + 1) * 1024 + lane * 16);
            bfrag vf = *(const bfrag*)(kb + 8192 + sub * 1024 + lane * 16);
            {   // q-frag 0
                f4 sa = {0.f, 0.f, 0.f, 0.f}, sb = {0.f, 0.f, 0.f, 0.f};
                sa = mfma_bf16(ka, qh0, sa);  sa = mfma_bf16(ka, ql0, sa);
                sa = mfma_bf16(la, qh0, sa);
                sb = mfma_bf16(kc2, qh0, sb); sb = mfma_bf16(kc2, ql0, sb);
                sb = mfma_bf16(lb, qh0, sb);
                float ea[4], eb[4];
#pragma unroll
                for (int r = 0; r < 4; ++r) {
                    ea[r] = fexp2(sa[r]); eb[r] = fexp2(sb[r]);
                    ls0 += ea[r] + eb[r];
                }
#pragma unroll
                for (int r = 0; r < 4; ++r) plswap16(ea[r], eb[r]);
                union { unsigned u[4]; bfrag v; } pf;
                pf.u[0] = pk_rne(ea[0], ea[1]); pf.u[1] = pk_rne(ea[2], ea[3]);
                pf.u[2] = pk_rne(eb[0], eb[1]); pf.u[3] = pk_rne(eb[2], eb[3]);
                o0 = mfma_bf16(pf.v, vf, o0);
            }
            {   // q-frag 1
                f4 sa = {0.f, 0.f, 0.f, 0.f}, sb = {0.f, 0.f, 0.f, 0.f};
                sa = mfma_bf16(ka, qh1, sa);  sa = mfma_bf16(ka, ql1, sa);
                sa = mfma_bf16(la, qh1, sa);
                sb = mfma_bf16(kc2, qh1, sb); sb = mfma_bf16(kc2, ql1, sb);
                sb = mfma_bf16(lb, qh1, sb);
                float ea[4], eb[4];
#pragma unroll
                for (int r = 0; r < 4; ++r) {
                    ea[r] = fexp2(sa[r]); eb[r] = fexp2(sb[r]);
                    ls1 += ea[r] + eb[r];
                }
#pragma unroll
                for (int r = 0; r < 4; ++r) plswap16(ea[r], eb[r]);
                union { unsigned u[4]; bfrag v; } pf;
                pf.u[0] = pk_rne(ea[0], ea[1]); pf.u[1] = pk_rne(ea[2], ea[3]);
                pf.u[2] = pk_rne(eb[0], eb[1]); pf.u[3] = pk_rne(eb[2], eb[3]);
                o1 = mfma_bf16(pf.v, vf, o1);
            }
        }
        cur ^= 1;
    }

    ls0 += __shfl_xor(ls0, 16, 64); ls0 += __shfl_xor(ls0, 32, 64);
    ls1 += __shfl_xor(ls1, 16, 64); ls1 += __shfl_xor(ls1, 32, 64);
    const int bbk = bh >> 3, h = bh & 7;
#pragma unroll
    for (int r = 0; r < 4; ++r) {
        float L0 = __shfl(ls0, qd * 4 + r, 64);
        float L1 = __shfl(ls1, qd * 4 + r, 64);
        int row = qd * 4 + r;
        xout[((size_t)(bbk * 2048 + q0 + row)) * 128 + h * 16 + c] = o0[r] / L0;
        xout[((size_t)(bbk * 2048 + q0 + 16 + row)) * 128 + h * 16 + c] = o1[r] / L1;
    }
}

// ---------- output projection ----------
// 256 blocks x 256 threads, 32 rows/block; lane: cg=4 cols, rs=4 rows.
__global__ __launch_bounds__(256) void k_out(
    const float* __restrict__ x, const float* __restrict__ Wo,
    const float* __restrict__ bo, float* __restrict__ out)
{
    __shared__ float xs[32][128];   // 16 KB
    const int tid = threadIdx.x;
    const int row0 = blockIdx.x * 32;
    for (int idx = tid; idx < 1024; idx += 256) {
        int r = idx >> 5, c4 = idx & 31;
        *(f4*)&xs[r][c4 * 4] = *(const f4*)(x + (size_t)(row0 + r) * 128 + c4 * 4);
    }
    __syncthreads();
    const int cg = tid & 31, rs = tid >> 5;
    float acc[4][4];
#pragma unroll
    for (int cc = 0; cc < 4; ++cc) {
        float bias = bo[cg * 4 + cc];
#pragma unroll
        for (int i = 0; i < 4; ++i) acc[i][cc] = bias;
    }
    const float* wbase = Wo + (size_t)(cg * 4) * 128;
#pragma unroll 4
    for (int dq = 0; dq < 32; ++dq) {
        f4 w0 = *(const f4*)(wbase + dq * 4);
        f4 w1 = *(const f4*)(wbase + 128 + dq * 4);
        f4 w2 = *(const f4*)(wbase + 256 + dq * 4);
        f4 w3 = *(const f4*)(wbase + 384 + dq * 4);
#pragma unroll
        for (int i = 0; i < 4; ++i) {
            f4 xr = *(const f4*)&xs[rs * 4 + i][dq * 4];
            acc[i][0] = fmaf(xr.x, w0.x, acc[i][0]); acc[i][0] = fmaf(xr.y, w0.y, acc[i][0]);
            acc[i][0] = fmaf(xr.z, w0.z, acc[i][0]); acc[i][0] = fmaf(xr.w, w0.w, acc[i][0]);
            acc[i][1] = fmaf(xr.x, w1.x, acc[i][1]); acc[i][1] = fmaf(xr.y, w1.y, acc[i][1]);
            acc[i][1] = fmaf(xr.z, w1.z, acc[i][1]); acc[i][1] = fmaf(xr.w, w1.w, acc[i][1]);
            acc[i][2] = fmaf(xr.x, w2.x, acc[i][2]); acc[i][2] = fmaf(xr.y, w2.y, acc[i][2]);
            acc[i][2] = fmaf(xr.z, w2.z, acc[i][2]); acc[i][2] = fmaf(xr.w, w2.w, acc[i][2]);
            acc[i][3] = fmaf(xr.x, w3.x, acc[i][3]); acc[i][3] = fmaf(xr.y, w3.y, acc[i][3]);
            acc[i][3] = fmaf(xr.z, w3.z, acc[i][3]); acc[i][3] = fmaf(xr.w, w3.w, acc[i][3]);
        }
    }
#pragma unroll
    for (int i = 0; i < 4; ++i) {
        f4 ov = {acc[i][0], acc[i][1], acc[i][2], acc[i][3]};
        *(f4*)(out + (size_t)(row0 + rs * 4 + i) * 128 + cg * 4) = ov;
    }
}

extern "C" void kernel_launch(void* const* d_in, const int* in_sizes, int n_in,
                              void* d_out, int out_size, void* d_ws, size_t ws_size,
                              hipStream_t stream)
{
    const float* query = (const float*)d_in[0];
    const float* key   = (const float*)d_in[1];
    const float* value = (const float*)d_in[2];
    const float* pos   = (const float*)d_in[3];
    const float* W0 = (const float*)d_in[4];
    const float* b0 = (const float*)d_in[5];
    const float* W1 = (const float*)d_in[6];
    const float* b1 = (const float*)d_in[7];
    const float* W2 = (const float*)d_in[8];
    const float* b2 = (const float*)d_in[9];
    const float* Wo = (const float*)d_in[10];
    const float* bo = (const float*)d_in[11];

    char* ws = (char*)d_ws;
    char* qbuf = ws + WS_QB;
    char* kv   = ws + WS_KV;
    float* x   = (float*)(ws + WS_X);
    float* out = (float*)d_out;

    k_proj<<<dim3(512), 320, 0, stream>>>(query, key, value, pos,
                                          W0, W1, W2, b0, b1, b2, qbuf, kv);
    k_attn<<<dim3(16, 32), 256, 0, stream>>>(qbuf, kv, x);
    k_out<<<dim3(256), 256, 0, stream>>>(x, Wo, bo, out);
}

// Round 5
// 148.509 us; speedup vs baseline: 1.2860x; 1.2860x over previous
//
#include <hip/hip_runtime.h>
#include <math.h>

#define LOG2E 1.44269504088896340736f

typedef __attribute__((ext_vector_type(8))) short bfrag;   // 8 x bf16
typedef __attribute__((ext_vector_type(4))) float f4;
typedef unsigned __attribute__((ext_vector_type(2))) u2;

// ---------- helpers ----------
__device__ __forceinline__ unsigned pk_trunc(float a, float b) {
    return (__float_as_uint(a) >> 16) | (__float_as_uint(b) & 0xFFFF0000u);
}
__device__ __forceinline__ unsigned pk_rne(float a, float b) {
    unsigned ua = __float_as_uint(a); ua += 0x7FFFu + ((ua >> 16) & 1u);
    unsigned ub = __float_as_uint(b); ub += 0x7FFFu + ((ub >> 16) & 1u);
    return (ua >> 16) | (ub & 0xFFFF0000u);
}
__device__ __forceinline__ float trunchi(float x) {
    return __uint_as_float(__float_as_uint(x) & 0xFFFF0000u);
}
__device__ __forceinline__ float fexp2(float x) {
#if __has_builtin(__builtin_amdgcn_exp2f)
    return __builtin_amdgcn_exp2f(x);
#else
    return exp2f(x);
#endif
}
// exchange: a's odd 16-lane rows <-> b's even 16-lane rows (VALU pipe on gfx950)
__device__ __forceinline__ void plswap16(float& a, float& b) {
#if __has_builtin(__builtin_amdgcn_permlane16_swap)
    u2 t = __builtin_amdgcn_permlane16_swap(__float_as_uint(a), __float_as_uint(b),
                                            false, false);
    a = __uint_as_float(t.x); b = __uint_as_float(t.y);
#else
    bool odd = (threadIdx.x >> 4) & 1;
    float bs = __shfl_xor(b, 16, 64);
    float as = __shfl_xor(a, 16, 64);
    float na = odd ? bs : a;
    float nb = odd ? b : as;
    a = na; b = nb;
#endif
}
// async global->LDS, 16B/lane; lds base wave-uniform, HW lands lane i at base+i*16
__device__ __forceinline__ void stage16(void* lds_base, const void* g) {
#if __has_builtin(__builtin_amdgcn_global_load_lds)
    __builtin_amdgcn_global_load_lds(
        (const __attribute__((address_space(1))) unsigned int*)g,
        (__attribute__((address_space(3))) unsigned int*)lds_base, 16, 0, 0);
#else
    int lane = threadIdx.x & 63;
    *(float4*)((char*)lds_base + lane * 16) = *(const float4*)g;
#endif
}
__device__ __forceinline__ f4 mfma_bf16(bfrag a, bfrag b, f4 c) {
    return __builtin_amdgcn_mfma_f32_16x16x32_bf16(a, b, c, 0, 0, 0);
}
// split 8 consecutive fp32 at g into hi/lo bf16 fragment halves
__device__ __forceinline__ void conv8(const float* __restrict__ g, bfrag& hi, bfrag& lo) {
    f4 a = *(const f4*)g;
    f4 b = *(const f4*)(g + 4);
    union { unsigned u[4]; bfrag v; } H, L;
    H.u[0] = pk_trunc(a.x, a.y); H.u[1] = pk_trunc(a.z, a.w);
    H.u[2] = pk_trunc(b.x, b.y); H.u[3] = pk_trunc(b.z, b.w);
    L.u[0] = pk_trunc(a.x - trunchi(a.x), a.y - trunchi(a.y));
    L.u[1] = pk_trunc(a.z - trunchi(a.z), a.w - trunchi(a.w));
    L.u[2] = pk_trunc(b.x - trunchi(b.x), b.y - trunchi(b.y));
    L.u[3] = pk_trunc(b.z - trunchi(b.z), b.w - trunchi(b.w));
    hi = H.v; lo = L.v;
}
// C-tile-pair (ea=dims/keys 0-15 tile, eb=16-31 tile) -> hi/lo frag image stores.
// plswap gives k-group -> block map {0,2,1,3}, consistently applied to q',k'
// (cancels in S) and matching attn's P/V key permutation.
__device__ __forceinline__ void store_qk(f4 ea, f4 eb, char* base, int lodelta, int lane) {
    float eah[4], eal[4], ebh[4], ebl[4];
#pragma unroll
    for (int r = 0; r < 4; ++r) {
        eah[r] = trunchi(ea[r]); eal[r] = ea[r] - eah[r];
        ebh[r] = trunchi(eb[r]); ebl[r] = eb[r] - ebh[r];
    }
#pragma unroll
    for (int r = 0; r < 4; ++r) { plswap16(eah[r], ebh[r]); plswap16(eal[r], ebl[r]); }
    union { unsigned u[4]; bfrag v; } H, L;
    H.u[0] = pk_trunc(eah[0], eah[1]); H.u[1] = pk_trunc(eah[2], eah[3]);
    H.u[2] = pk_trunc(ebh[0], ebh[1]); H.u[3] = pk_trunc(ebh[2], ebh[3]);
    L.u[0] = pk_trunc(eal[0], eal[1]); L.u[1] = pk_trunc(eal[2], eal[3]);
    L.u[2] = pk_trunc(ebl[0], ebl[1]); L.u[3] = pk_trunc(ebl[2], ebl[3]);
    *(bfrag*)(base + lane * 16) = H.v;
    *(bfrag*)(base + lodelta + lane * 16) = L.v;
}

// ---------- workspace byte offsets ----------
// qb:   [bh][128 panels][hi 1KB | lo 1KB]          = 8,388,608
// kv:   [bh][32 chunks][khi 4K|klo 4K|vt 2K]       = 10,485,760
// x:    [B][S][128] fp32                           = 4,194,304
// wimg: 5 x [8 tiles][4 kg][hi 1KB|lo 1KB]         = 327,680
#define WS_QB 0u
#define WS_KV 8388608u
#define WS_X  18874368u
#define WS_WI 23068672u

// ---------- weight fragment prep ----------
// img: 0 = 0.25*log2e*W0 (q half), 1 = log2e*W0 (pos_q half), 2 = W1, 3 = W2,
// 4 = Wo. Frag: lane&15 -> W row (within 16-row tile), holds 8 indims
// kg*32+(lane>>4)*8.. as bf16 hi/lo. Serves as A-operand (q'/k') and
// B-operand (v, out) identically.
__global__ __launch_bounds__(256) void w_prep(
    const float* __restrict__ W0, const float* __restrict__ W1,
    const float* __restrict__ W2, const float* __restrict__ Wo,
    char* __restrict__ wimg)
{
    int wid = blockIdx.x * 4 + (threadIdx.x >> 6);   // 0..159
    int lane = threadIdx.x & 63;
    int img = wid >> 5, rem = wid & 31, tile = rem >> 2, kg = rem & 3;
    const float* W = (img <= 1) ? W0 : (img == 2) ? W1 : (img == 3) ? W2 : Wo;
    float s = (img == 0) ? 0.25f * LOG2E : (img == 1) ? LOG2E : 1.0f;
    int n = lane & 15, qd = lane >> 4;
    const float* g = W + (size_t)(tile * 16 + n) * 128 + kg * 32 + qd * 8;
    f4 a = *(const f4*)g, b = *(const f4*)(g + 4);
    a.x *= s; a.y *= s; a.z *= s; a.w *= s;
    b.x *= s; b.y *= s; b.z *= s; b.w *= s;
    union { unsigned u[4]; bfrag v; } H, L;
    H.u[0] = pk_trunc(a.x, a.y); H.u[1] = pk_trunc(a.z, a.w);
    H.u[2] = pk_trunc(b.x, b.y); H.u[3] = pk_trunc(b.z, b.w);
    L.u[0] = pk_trunc(a.x - trunchi(a.x), a.y - trunchi(a.y));
    L.u[1] = pk_trunc(a.z - trunchi(a.z), a.w - trunchi(a.w));
    L.u[2] = pk_trunc(b.x - trunchi(b.x), b.y - trunchi(b.y));
    L.u[3] = pk_trunc(b.z - trunchi(b.z), b.w - trunchi(b.w));
    char* dst = wimg + img * 65536 + tile * 8192 + kg * 2048;
    *(bfrag*)(dst + lane * 16) = H.v;
    *(bfrag*)(dst + 1024 + lane * 16) = L.v;
}

// ---------- MFMA projections ----------
// wave-task = (bh, s32): 32 seq rows. q'/k' transposed GEMM C[dim][seq]
// (A = W-frags, B = X-frags); v normal C[key][dim] (A = X, B = W2).
// hi/lo 3-combo per tile (12 MFMA / 16x16 tile over K=128).
__global__ __launch_bounds__(256) void k_proj(
    const float* __restrict__ query, const float* __restrict__ key,
    const float* __restrict__ value, const float* __restrict__ pos,
    const float* __restrict__ b0, const float* __restrict__ b1,
    const float* __restrict__ b2,
    const char* __restrict__ wimg, char* __restrict__ qb, char* __restrict__ kv)
{
    const int tid = threadIdx.x;
    const int w = tid >> 6, lane = tid & 63;
    const int n = lane & 15, qd = lane >> 4;
    const int bid = blockIdx.x;          // 0..511
    const int bh = bid >> 4, b = bh >> 3, h = bh & 7;
    const int s32 = ((bid & 15) << 2) | w;   // 0..63

    // ---- phase Q: q' = [0.25L*(query W0^T + b0) || L*(pos W0^T + b0)] ----
    {
        bfrag wqh[4], wql[4], wph[4], wpl[4];
#pragma unroll
        for (int kg = 0; kg < 4; ++kg) {
            const char* wb = wimg + 0 * 65536 + h * 8192 + kg * 2048;
            wqh[kg] = *(const bfrag*)(wb + lane * 16);
            wql[kg] = *(const bfrag*)(wb + 1024 + lane * 16);
            const char* pb = wimg + 1 * 65536 + h * 8192 + kg * 2048;
            wph[kg] = *(const bfrag*)(pb + lane * 16);
            wpl[kg] = *(const bfrag*)(pb + 1024 + lane * 16);
        }
        float bq[4], bp[4];
#pragma unroll
        for (int r = 0; r < 4; ++r) {
            float bv = b0[h * 16 + qd * 4 + r];
            bq[r] = 0.25f * LOG2E * bv; bp[r] = LOG2E * bv;
        }
#pragma unroll
        for (int pp = 0; pp < 2; ++pp) {
            int p = 2 * s32 + pp;
            size_t rowg = (size_t)(b * 2048 + p * 16 + n) * 128 + qd * 8;
            f4 cq = {bq[0], bq[1], bq[2], bq[3]};
            f4 cp = {bp[0], bp[1], bp[2], bp[3]};
#pragma unroll
            for (int kg = 0; kg < 4; ++kg) {
                bfrag xh, xl, ph, pl;
                conv8(query + rowg + kg * 32, xh, xl);
                conv8(pos + rowg + kg * 32, ph, pl);
                cq = mfma_bf16(wqh[kg], xh, cq);
                cq = mfma_bf16(wqh[kg], xl, cq);
                cq = mfma_bf16(wql[kg], xh, cq);
                cp = mfma_bf16(wph[kg], ph, cp);
                cp = mfma_bf16(wph[kg], pl, cp);
                cp = mfma_bf16(wpl[kg], ph, cp);
            }
            store_qk(cq, cp, qb + (size_t)bh * 262144 + (size_t)p * 2048, 1024, lane);
        }
    }
    // ---- phase K: k' = [(key W1^T + b1) || (pos W1^T + b1)] ----
    {
        bfrag w1h[4], w1l[4];
#pragma unroll
        for (int kg = 0; kg < 4; ++kg) {
            const char* wb = wimg + 2 * 65536 + h * 8192 + kg * 2048;
            w1h[kg] = *(const bfrag*)(wb + lane * 16);
            w1l[kg] = *(const bfrag*)(wb + 1024 + lane * 16);
        }
        float bk[4];
#pragma unroll
        for (int r = 0; r < 4; ++r) bk[r] = b1[h * 16 + qd * 4 + r];
#pragma unroll
        for (int pp = 0; pp < 2; ++pp) {
            int p = 2 * s32 + pp;
            size_t rowg = (size_t)(b * 2048 + p * 16 + n) * 128 + qd * 8;
            f4 ck = {bk[0], bk[1], bk[2], bk[3]};
            f4 cpk = {bk[0], bk[1], bk[2], bk[3]};
#pragma unroll
            for (int kg = 0; kg < 4; ++kg) {
                bfrag xh, xl, ph, pl;
                conv8(key + rowg + kg * 32, xh, xl);
                conv8(pos + rowg + kg * 32, ph, pl);
                ck = mfma_bf16(w1h[kg], xh, ck);
                ck = mfma_bf16(w1h[kg], xl, ck);
                ck = mfma_bf16(w1l[kg], xh, ck);
                cpk = mfma_bf16(w1h[kg], ph, cpk);
                cpk = mfma_bf16(w1h[kg], pl, cpk);
                cpk = mfma_bf16(w1l[kg], ph, cpk);
            }
            store_qk(ck, cpk,
                     kv + (size_t)bh * 327680 + (size_t)(p >> 2) * 10240 + (p & 3) * 1024,
                     4096, lane);
        }
    }
    // ---- phase V: vt = value W2^T + b2 (normal orientation, RNE bf16) ----
    {
        bfrag w2h[4], w2l[4];
#pragma unroll
        for (int kg = 0; kg < 4; ++kg) {
            const char* wb = wimg + 3 * 65536 + h * 8192 + kg * 2048;
            w2h[kg] = *(const bfrag*)(wb + lane * 16);
            w2l[kg] = *(const bfrag*)(wb + 1024 + lane * 16);
        }
        float bv = b2[h * 16 + n];
        f4 ca = {bv, bv, bv, bv};
        f4 cb = {bv, bv, bv, bv};
#pragma unroll
        for (int pp = 0; pp < 2; ++pp) {
            size_t rowg = (size_t)(b * 2048 + (2 * s32 + pp) * 16 + n) * 128 + qd * 8;
#pragma unroll
            for (int kg = 0; kg < 4; ++kg) {
                bfrag ah, al;
                conv8(value + rowg + kg * 32, ah, al);
                if (pp == 0) {
                    ca = mfma_bf16(ah, w2h[kg], ca);
                    ca = mfma_bf16(al, w2h[kg], ca);
                    ca = mfma_bf16(ah, w2l[kg], ca);
                } else {
                    cb = mfma_bf16(ah, w2h[kg], cb);
                    cb = mfma_bf16(al, w2h[kg], cb);
                    cb = mfma_bf16(ah, w2l[kg], cb);
                }
            }
        }
        float va[4], vb[4];
#pragma unroll
        for (int r = 0; r < 4; ++r) { va[r] = ca[r]; vb[r] = cb[r]; }
#pragma unroll
        for (int r = 0; r < 4; ++r) plswap16(va[r], vb[r]);
        union { unsigned u[4]; bfrag v; } P;
        P.u[0] = pk_rne(va[0], va[1]); P.u[1] = pk_rne(va[2], va[3]);
        P.u[2] = pk_rne(vb[0], vb[1]); P.u[3] = pk_rne(vb[2], vb[3]);
        *(bfrag*)(kv + (size_t)bh * 327680 + (size_t)(s32 >> 1) * 10240
                  + 8192 + (s32 & 1) * 1024 + lane * 16) = P.v;
    }
}

// ---------- fused flash attention ----------
// Block = 4 waves x 32 q-rows; grid (16, 32 bh). Per 64-key chunk: stage 10KB
// (double-buffered, explicit vmcnt(0) drain before barrier); S^T = k'(A) x
// q'(B), 3 MFMAs/panel hi/lo; exp2; C->A via plswap (key-permuted, matches
// vt); PV 1 MFMA + ones-MFMA for the row-sum l (lane-aligned with o, and
// exactly consistent with truncated P). No online max (scores bounded).
__global__ __launch_bounds__(256) void k_attn(
    const char* __restrict__ qb, const char* __restrict__ kvg,
    float* __restrict__ xout)
{
    __shared__ __align__(16) char kbuf[2][10240];
    const int tid = threadIdx.x;
    const int w = tid >> 6, lane = tid & 63;
    const int c = lane & 15, qd = lane >> 4;
    const int bh = blockIdx.y;
    const int q0 = blockIdx.x * 128 + w * 32;

    const char* qpb = qb + (size_t)bh * 262144 + (size_t)(q0 >> 4) * 2048;
    bfrag qh0 = *(const bfrag*)(qpb + lane * 16);
    bfrag ql0 = *(const bfrag*)(qpb + 1024 + lane * 16);
    bfrag qh1 = *(const bfrag*)(qpb + 2048 + lane * 16);
    bfrag ql1 = *(const bfrag*)(qpb + 3072 + lane * 16);

    const char* kvb = kvg + (size_t)bh * 327680;

    union { unsigned u[4]; bfrag v; } onesu;
    onesu.u[0] = 0x3F803F80u; onesu.u[1] = 0x3F803F80u;
    onesu.u[2] = 0x3F803F80u; onesu.u[3] = 0x3F803F80u;
    const bfrag ones = onesu.v;

    f4 o0 = {0.f, 0.f, 0.f, 0.f}, o1 = {0.f, 0.f, 0.f, 0.f};
    f4 l0 = {0.f, 0.f, 0.f, 0.f}, l1 = {0.f, 0.f, 0.f, 0.f};

    auto stage = [&](char* db, const char* gsrc) {
        stage16(db + w * 1024, gsrc + w * 1024 + lane * 16);
        stage16(db + (w + 4) * 1024, gsrc + (w + 4) * 1024 + lane * 16);
        if (w < 2)
            stage16(db + (8 + w) * 1024, gsrc + (8 + w) * 1024 + lane * 16);
    };

    stage(kbuf[0], kvb);
    int cur = 0;
    for (int ch = 0; ch < 32; ++ch) {
        asm volatile("s_waitcnt vmcnt(0)" ::: "memory");
        __syncthreads();
        if (ch < 31) stage(kbuf[cur ^ 1], kvb + (size_t)(ch + 1) * 10240);
        const char* kb = kbuf[cur];
#pragma unroll
        for (int sub = 0; sub < 2; ++sub) {
            bfrag ka = *(const bfrag*)(kb + (2 * sub) * 1024 + lane * 16);
            bfrag kc2 = *(const bfrag*)(kb + (2 * sub + 1) * 1024 + lane * 16);
            bfrag la = *(const bfrag*)(kb + 4096 + (2 * sub) * 1024 + lane * 16);
            bfrag lb = *(const bfrag*)(kb + 4096 + (2 * sub + 1) * 1024 + lane * 16);
            bfrag vf = *(const bfrag*)(kb + 8192 + sub * 1024 + lane * 16);
            {   // q-frag 0
                f4 sa = {0.f, 0.f, 0.f, 0.f}, sb = {0.f, 0.f, 0.f, 0.f};
                sa = mfma_bf16(ka, qh0, sa);  sa = mfma_bf16(ka, ql0, sa);
                sa = mfma_bf16(la, qh0, sa);
                sb = mfma_bf16(kc2, qh0, sb); sb = mfma_bf16(kc2, ql0, sb);
                sb = mfma_bf16(lb, qh0, sb);
                float ea[4], eb[4];
#pragma unroll
                for (int r = 0; r < 4; ++r) { ea[r] = fexp2(sa[r]); eb[r] = fexp2(sb[r]); }
#pragma unroll
                for (int r = 0; r < 4; ++r) plswap16(ea[r], eb[r]);
                union { unsigned u[4]; bfrag v; } pf;
                pf.u[0] = pk_trunc(ea[0], ea[1]); pf.u[1] = pk_trunc(ea[2], ea[3]);
                pf.u[2] = pk_trunc(eb[0], eb[1]); pf.u[3] = pk_trunc(eb[2], eb[3]);
                o0 = mfma_bf16(pf.v, vf, o0);
                l0 = mfma_bf16(pf.v, ones, l0);
            }
            {   // q-frag 1
                f4 sa = {0.f, 0.f, 0.f, 0.f}, sb = {0.f, 0.f, 0.f, 0.f};
                sa = mfma_bf16(ka, qh1, sa);  sa = mfma_bf16(ka, ql1, sa);
                sa = mfma_bf16(la, qh1, sa);
                sb = mfma_bf16(kc2, qh1, sb); sb = mfma_bf16(kc2, ql1, sb);
                sb = mfma_bf16(lb, qh1, sb);
                float ea[4], eb[4];
#pragma unroll
                for (int r = 0; r < 4; ++r) { ea[r] = fexp2(sa[r]); eb[r] = fexp2(sb[r]); }
#pragma unroll
                for (int r = 0; r < 4; ++r) plswap16(ea[r], eb[r]);
                union { unsigned u[4]; bfrag v; } pf;
                pf.u[0] = pk_trunc(ea[0], ea[1]); pf.u[1] = pk_trunc(ea[2], ea[3]);
                pf.u[2] = pk_trunc(eb[0], eb[1]); pf.u[3] = pk_trunc(eb[2], eb[3]);
                o1 = mfma_bf16(pf.v, vf, o1);
                l1 = mfma_bf16(pf.v, ones, l1);
            }
        }
        cur ^= 1;
    }

    const int bbk = bh >> 3, h = bh & 7;
#pragma unroll
    for (int r = 0; r < 4; ++r) {
        int row = qd * 4 + r;
        xout[((size_t)(bbk * 2048 + q0 + row)) * 128 + h * 16 + c] = o0[r] / l0[r];
        xout[((size_t)(bbk * 2048 + q0 + 16 + row)) * 128 + h * 16 + c] = o1[r] / l1[r];
    }
}

// ---------- output projection (MFMA) ----------
// wave-task = 16 seq rows x 128 outcols. A = x hi/lo (converted inline),
// B = Wo frag image (img 4). C[m=seq][n=outcol].
__global__ __launch_bounds__(256) void k_out(
    const float* __restrict__ x, const char* __restrict__ wimg,
    const float* __restrict__ bo, float* __restrict__ out)
{
    const int tid = threadIdx.x;
    const int w = tid >> 6, lane = tid & 63;
    const int n = lane & 15, qd = lane >> 4;
    const int row0 = (blockIdx.x * 4 + w) * 16;

    bfrag xh[4], xl[4];
#pragma unroll
    for (int kg = 0; kg < 4; ++kg)
        conv8(x + (size_t)(row0 + n) * 128 + kg * 32 + qd * 8, xh[kg], xl[kg]);

#pragma unroll
    for (int t = 0; t < 8; ++t) {
        float bv = bo[t * 16 + n];
        f4 cacc = {bv, bv, bv, bv};
#pragma unroll
        for (int kg = 0; kg < 4; ++kg) {
            const char* wb = wimg + 4 * 65536 + t * 8192 + kg * 2048;
            bfrag wh = *(const bfrag*)(wb + lane * 16);
            bfrag wl = *(const bfrag*)(wb + 1024 + lane * 16);
            cacc = mfma_bf16(xh[kg], wh, cacc);
            cacc = mfma_bf16(xl[kg], wh, cacc);
            cacc = mfma_bf16(xh[kg], wl, cacc);
        }
#pragma unroll
        for (int r = 0; r < 4; ++r)
            out[(size_t)(row0 + qd * 4 + r) * 128 + t * 16 + n] = cacc[r];
    }
}

extern "C" void kernel_launch(void* const* d_in, const int* in_sizes, int n_in,
                              void* d_out, int out_size, void* d_ws, size_t ws_size,
                              hipStream_t stream)
{
    const float* query = (const float*)d_in[0];
    const float* key   = (const float*)d_in[1];
    const float* value = (const float*)d_in[2];
    const float* pos   = (const float*)d_in[3];
    const float* W0 = (const float*)d_in[4];
    const float* b0 = (const float*)d_in[5];
    const float* W1 = (const float*)d_in[6];
    const float* b1 = (const float*)d_in[7];
    const float* W2 = (const float*)d_in[8];
    const float* b2 = (const float*)d_in[9];
    const float* Wo = (const float*)d_in[10];
    const float* bo = (const float*)d_in[11];

    char* ws = (char*)d_ws;
    char* qbuf = ws + WS_QB;
    char* kv   = ws + WS_KV;
    float* x   = (float*)(ws + WS_X);
    char* wimg = ws + WS_WI;
    float* out = (float*)d_out;

    w_prep<<<dim3(40), 256, 0, stream>>>(W0, W1, W2, Wo, wimg);
    k_proj<<<dim3(512), 256, 0, stream>>>(query, key, value, pos, b0, b1, b2,
                                          wimg, qbuf, kv);
    k_attn<<<dim3(16, 32), 256, 0, stream>>>(qbuf, kv, x);
    k_out<<<dim3(128), 256, 0, stream>>>(x, wimg, bo, out);
}

// Round 6
// 144.594 us; speedup vs baseline: 1.3208x; 1.0271x over previous
//
#include <hip/hip_runtime.h>
#include <math.h>

#define LOG2E 1.44269504088896340736f

typedef __attribute__((ext_vector_type(8))) short bfrag;   // 8 x bf16
typedef __attribute__((ext_vector_type(4))) float f4;
typedef unsigned __attribute__((ext_vector_type(2))) u2;

// ---------- helpers ----------
__device__ __forceinline__ unsigned pk_trunc(float a, float b) {
    return (__float_as_uint(a) >> 16) | (__float_as_uint(b) & 0xFFFF0000u);
}
__device__ __forceinline__ unsigned pk_rne(float a, float b) {
    unsigned ua = __float_as_uint(a); ua += 0x7FFFu + ((ua >> 16) & 1u);
    unsigned ub = __float_as_uint(b); ub += 0x7FFFu + ((ub >> 16) & 1u);
    return (ua >> 16) | (ub & 0xFFFF0000u);
}
__device__ __forceinline__ float trunchi(float x) {
    return __uint_as_float(__float_as_uint(x) & 0xFFFF0000u);
}
__device__ __forceinline__ float fexp2(float x) {
#if __has_builtin(__builtin_amdgcn_exp2f)
    return __builtin_amdgcn_exp2f(x);
#else
    return exp2f(x);
#endif
}
// exchange: a's odd 16-lane rows <-> b's even 16-lane rows (VALU pipe on gfx950)
__device__ __forceinline__ void plswap16(float& a, float& b) {
#if __has_builtin(__builtin_amdgcn_permlane16_swap)
    u2 t = __builtin_amdgcn_permlane16_swap(__float_as_uint(a), __float_as_uint(b),
                                            false, false);
    a = __uint_as_float(t.x); b = __uint_as_float(t.y);
#else
    bool odd = (threadIdx.x >> 4) & 1;
    float bs = __shfl_xor(b, 16, 64);
    float as = __shfl_xor(a, 16, 64);
    float na = odd ? bs : a;
    float nb = odd ? b : as;
    a = na; b = nb;
#endif
}
// async global->LDS, 16B/lane; lds base wave-uniform, HW lands lane i at base+i*16
__device__ __forceinline__ void stage16(void* lds_base, const void* g) {
#if __has_builtin(__builtin_amdgcn_global_load_lds)
    __builtin_amdgcn_global_load_lds(
        (const __attribute__((address_space(1))) unsigned int*)g,
        (__attribute__((address_space(3))) unsigned int*)lds_base, 16, 0, 0);
#else
    int lane = threadIdx.x & 63;
    *(float4*)((char*)lds_base + lane * 16) = *(const float4*)g;
#endif
}
__device__ __forceinline__ f4 mfma_bf16(bfrag a, bfrag b, f4 c) {
    return __builtin_amdgcn_mfma_f32_16x16x32_bf16(a, b, c, 0, 0, 0);
}
// split 8 consecutive fp32 at g into hi/lo bf16 fragment halves
__device__ __forceinline__ void conv8(const float* __restrict__ g, bfrag& hi, bfrag& lo) {
    f4 a = *(const f4*)g;
    f4 b = *(const f4*)(g + 4);
    union { unsigned u[4]; bfrag v; } H, L;
    H.u[0] = pk_trunc(a.x, a.y); H.u[1] = pk_trunc(a.z, a.w);
    H.u[2] = pk_trunc(b.x, b.y); H.u[3] = pk_trunc(b.z, b.w);
    L.u[0] = pk_trunc(a.x - trunchi(a.x), a.y - trunchi(a.y));
    L.u[1] = pk_trunc(a.z - trunchi(a.z), a.w - trunchi(a.w));
    L.u[2] = pk_trunc(b.x - trunchi(b.x), b.y - trunchi(b.y));
    L.u[3] = pk_trunc(b.z - trunchi(b.z), b.w - trunchi(b.w));
    hi = H.v; lo = L.v;
}
// q': C-tile-pair -> hi/lo frag image stores (plswap k-group map {0,2,1,3};
// applied consistently to q',k' so it cancels in S; matches P/V permutation).
__device__ __forceinline__ void store_q(f4 ea, f4 eb, char* base, int lodelta, int lane) {
    float eah[4], eal[4], ebh[4], ebl[4];
#pragma unroll
    for (int r = 0; r < 4; ++r) {
        eah[r] = trunchi(ea[r]); eal[r] = ea[r] - eah[r];
        ebh[r] = trunchi(eb[r]); ebl[r] = eb[r] - ebh[r];
    }
#pragma unroll
    for (int r = 0; r < 4; ++r) { plswap16(eah[r], ebh[r]); plswap16(eal[r], ebl[r]); }
    union { unsigned u[4]; bfrag v; } H, L;
    H.u[0] = pk_trunc(eah[0], eah[1]); H.u[1] = pk_trunc(eah[2], eah[3]);
    H.u[2] = pk_trunc(ebh[0], ebh[1]); H.u[3] = pk_trunc(ebh[2], ebh[3]);
    L.u[0] = pk_trunc(eal[0], eal[1]); L.u[1] = pk_trunc(eal[2], eal[3]);
    L.u[2] = pk_trunc(ebl[0], ebl[1]); L.u[3] = pk_trunc(ebl[2], ebl[3]);
    *(bfrag*)(base + lane * 16) = H.v;
    *(bfrag*)(base + lodelta + lane * 16) = L.v;
}
// k'/v: C-tile-pair -> single RNE bf16 frag store
__device__ __forceinline__ void store_rne(f4 ea, f4 eb, char* base, int lane) {
    float a[4], b[4];
#pragma unroll
    for (int r = 0; r < 4; ++r) { a[r] = ea[r]; b[r] = eb[r]; }
#pragma unroll
    for (int r = 0; r < 4; ++r) plswap16(a[r], b[r]);
    union { unsigned u[4]; bfrag v; } P;
    P.u[0] = pk_rne(a[0], a[1]); P.u[1] = pk_rne(a[2], a[3]);
    P.u[2] = pk_rne(b[0], b[1]); P.u[3] = pk_rne(b[2], b[3]);
    *(bfrag*)(base + lane * 16) = P.v;
}

// ---------- workspace byte offsets ----------
// qb:   [bh][128 panels][hi 1KB | lo 1KB]            = 8,388,608
// kv:   [bh][16 chunks][k 8KB | vt 4KB]  (128 keys)  = 6,291,456
// x:    [B][S][128] fp32                             = 4,194,304
// wimg: 5 x [8 tiles][4 kg][hi 1KB|lo 1KB]           = 327,680
#define WS_QB 0u
#define WS_KV 8388608u
#define WS_X  14680064u
#define WS_WI 18874368u

// ---------- weight fragment prep ----------
// img: 0 = 0.25*log2e*W0, 1 = log2e*W0, 2 = W1, 3 = W2, 4 = Wo.
__global__ __launch_bounds__(256) void w_prep(
    const float* __restrict__ W0, const float* __restrict__ W1,
    const float* __restrict__ W2, const float* __restrict__ Wo,
    char* __restrict__ wimg)
{
    int wid = blockIdx.x * 4 + (threadIdx.x >> 6);   // 0..159
    int lane = threadIdx.x & 63;
    int img = wid >> 5, rem = wid & 31, tile = rem >> 2, kg = rem & 3;
    const float* W = (img <= 1) ? W0 : (img == 2) ? W1 : (img == 3) ? W2 : Wo;
    float s = (img == 0) ? 0.25f * LOG2E : (img == 1) ? LOG2E : 1.0f;
    int n = lane & 15, qd = lane >> 4;
    const float* g = W + (size_t)(tile * 16 + n) * 128 + kg * 32 + qd * 8;
    f4 a = *(const f4*)g, b = *(const f4*)(g + 4);
    a.x *= s; a.y *= s; a.z *= s; a.w *= s;
    b.x *= s; b.y *= s; b.z *= s; b.w *= s;
    union { unsigned u[4]; bfrag v; } H, L;
    H.u[0] = pk_trunc(a.x, a.y); H.u[1] = pk_trunc(a.z, a.w);
    H.u[2] = pk_trunc(b.x, b.y); H.u[3] = pk_trunc(b.z, b.w);
    L.u[0] = pk_trunc(a.x - trunchi(a.x), a.y - trunchi(a.y));
    L.u[1] = pk_trunc(a.z - trunchi(a.z), a.w - trunchi(a.w));
    L.u[2] = pk_trunc(b.x - trunchi(b.x), b.y - trunchi(b.y));
    L.u[3] = pk_trunc(b.z - trunchi(b.z), b.w - trunchi(b.w));
    char* dst = wimg + img * 65536 + tile * 8192 + kg * 2048;
    *(bfrag*)(dst + lane * 16) = H.v;
    *(bfrag*)(dst + 1024 + lane * 16) = L.v;
}

// ---------- MFMA projections ----------
// wave-task = (bh, s32): 32 seq rows. q'/k' transposed GEMM C[dim][seq]
// (A = W-frags, B = X-frags); v normal C[key][dim] (A = X, B = W2).
// q' stored hi/lo; k'/v stored single RNE bf16.
__global__ __launch_bounds__(256) void k_proj(
    const float* __restrict__ query, const float* __restrict__ key,
    const float* __restrict__ value, const float* __restrict__ pos,
    const float* __restrict__ b0, const float* __restrict__ b1,
    const float* __restrict__ b2,
    const char* __restrict__ wimg, char* __restrict__ qb, char* __restrict__ kv)
{
    const int tid = threadIdx.x;
    const int w = tid >> 6, lane = tid & 63;
    const int n = lane & 15, qd = lane >> 4;
    const int bid = blockIdx.x;          // 0..511
    const int bh = bid >> 4, b = bh >> 3, h = bh & 7;
    const int s32 = ((bid & 15) << 2) | w;   // 0..63

    // ---- phase Q: q' = [0.25L*(query W0^T + b0) || L*(pos W0^T + b0)] ----
    {
        bfrag wqh[4], wql[4], wph[4], wpl[4];
#pragma unroll
        for (int kg = 0; kg < 4; ++kg) {
            const char* wb = wimg + 0 * 65536 + h * 8192 + kg * 2048;
            wqh[kg] = *(const bfrag*)(wb + lane * 16);
            wql[kg] = *(const bfrag*)(wb + 1024 + lane * 16);
            const char* pb = wimg + 1 * 65536 + h * 8192 + kg * 2048;
            wph[kg] = *(const bfrag*)(pb + lane * 16);
            wpl[kg] = *(const bfrag*)(pb + 1024 + lane * 16);
        }
        float bq[4], bp[4];
#pragma unroll
        for (int r = 0; r < 4; ++r) {
            float bv = b0[h * 16 + qd * 4 + r];
            bq[r] = 0.25f * LOG2E * bv; bp[r] = LOG2E * bv;
        }
#pragma unroll
        for (int pp = 0; pp < 2; ++pp) {
            int p = 2 * s32 + pp;
            size_t rowg = (size_t)(b * 2048 + p * 16 + n) * 128 + qd * 8;
            f4 cq = {bq[0], bq[1], bq[2], bq[3]};
            f4 cp = {bp[0], bp[1], bp[2], bp[3]};
#pragma unroll
            for (int kg = 0; kg < 4; ++kg) {
                bfrag xh, xl, ph, pl;
                conv8(query + rowg + kg * 32, xh, xl);
                conv8(pos + rowg + kg * 32, ph, pl);
                cq = mfma_bf16(wqh[kg], xh, cq);
                cq = mfma_bf16(wqh[kg], xl, cq);
                cq = mfma_bf16(wql[kg], xh, cq);
                cp = mfma_bf16(wph[kg], ph, cp);
                cp = mfma_bf16(wph[kg], pl, cp);
                cp = mfma_bf16(wpl[kg], ph, cp);
            }
            store_q(cq, cp, qb + (size_t)bh * 262144 + (size_t)p * 2048, 1024, lane);
        }
    }
    // ---- phase K: k' = [(key W1^T + b1) || (pos W1^T + b1)], RNE bf16 ----
    {
        bfrag w1h[4], w1l[4];
#pragma unroll
        for (int kg = 0; kg < 4; ++kg) {
            const char* wb = wimg + 2 * 65536 + h * 8192 + kg * 2048;
            w1h[kg] = *(const bfrag*)(wb + lane * 16);
            w1l[kg] = *(const bfrag*)(wb + 1024 + lane * 16);
        }
        float bk[4];
#pragma unroll
        for (int r = 0; r < 4; ++r) bk[r] = b1[h * 16 + qd * 4 + r];
#pragma unroll
        for (int pp = 0; pp < 2; ++pp) {
            int p = 2 * s32 + pp;
            size_t rowg = (size_t)(b * 2048 + p * 16 + n) * 128 + qd * 8;
            f4 ck = {bk[0], bk[1], bk[2], bk[3]};
            f4 cpk = {bk[0], bk[1], bk[2], bk[3]};
#pragma unroll
            for (int kg = 0; kg < 4; ++kg) {
                bfrag xh, xl, ph, pl;
                conv8(key + rowg + kg * 32, xh, xl);
                conv8(pos + rowg + kg * 32, ph, pl);
                ck = mfma_bf16(w1h[kg], xh, ck);
                ck = mfma_bf16(w1h[kg], xl, ck);
                ck = mfma_bf16(w1l[kg], xh, ck);
                cpk = mfma_bf16(w1h[kg], ph, cpk);
                cpk = mfma_bf16(w1h[kg], pl, cpk);
                cpk = mfma_bf16(w1l[kg], ph, cpk);
            }
            store_rne(ck, cpk,
                      kv + (size_t)bh * 196608 + (size_t)(p >> 3) * 12288 + (p & 7) * 1024,
                      lane);
        }
    }
    // ---- phase V: vt = value W2^T + b2 (normal orientation, RNE bf16) ----
    {
        bfrag w2h[4], w2l[4];
#pragma unroll
        for (int kg = 0; kg < 4; ++kg) {
            const char* wb = wimg + 3 * 65536 + h * 8192 + kg * 2048;
            w2h[kg] = *(const bfrag*)(wb + lane * 16);
            w2l[kg] = *(const bfrag*)(wb + 1024 + lane * 16);
        }
        float bv = b2[h * 16 + n];
        f4 ca = {bv, bv, bv, bv};
        f4 cb = {bv, bv, bv, bv};
#pragma unroll
        for (int pp = 0; pp < 2; ++pp) {
            size_t rowg = (size_t)(b * 2048 + (2 * s32 + pp) * 16 + n) * 128 + qd * 8;
#pragma unroll
            for (int kg = 0; kg < 4; ++kg) {
                bfrag ah, al;
                conv8(value + rowg + kg * 32, ah, al);
                if (pp == 0) {
                    ca = mfma_bf16(ah, w2h[kg], ca);
                    ca = mfma_bf16(al, w2h[kg], ca);
                    ca = mfma_bf16(ah, w2l[kg], ca);
                } else {
                    cb = mfma_bf16(ah, w2h[kg], cb);
                    cb = mfma_bf16(al, w2h[kg], cb);
                    cb = mfma_bf16(ah, w2l[kg], cb);
                }
            }
        }
        store_rne(ca, cb,
                  kv + (size_t)bh * 196608 + (size_t)(s32 >> 2) * 12288
                  + 8192 + (s32 & 3) * 1024, lane);
    }
}

// ---------- fused flash attention ----------
// Block = 4 waves x 32 q-rows; grid (16, 32 bh). Per 128-key chunk: stage
// 12KB [k 8K | vt 4K] double-buffered (3 wave-uniform stage16/wave, explicit
// vmcnt(0) drain before barrier — correctness-critical, see R3/R4); per
// 32-key sub: S^T = k(A) x q'hi/lo(B) 2 MFMAs/panel; exp2; C->A via plswap
// (key-permuted, matches vt); PV MFMA + ones-MFMA row-sum (consistent with
// truncated P). No online max (scores bounded).
__global__ __launch_bounds__(256) void k_attn(
    const char* __restrict__ qb, const char* __restrict__ kvg,
    float* __restrict__ xout)
{
    __shared__ __align__(16) char kbuf[2][12288];
    const int tid = threadIdx.x;
    const int w = tid >> 6, lane = tid & 63;
    const int c = lane & 15, qd = lane >> 4;
    const int bh = blockIdx.y;
    const int q0 = blockIdx.x * 128 + w * 32;

    const char* qpb = qb + (size_t)bh * 262144 + (size_t)(q0 >> 4) * 2048;
    bfrag qh0 = *(const bfrag*)(qpb + lane * 16);
    bfrag ql0 = *(const bfrag*)(qpb + 1024 + lane * 16);
    bfrag qh1 = *(const bfrag*)(qpb + 2048 + lane * 16);
    bfrag ql1 = *(const bfrag*)(qpb + 3072 + lane * 16);

    const char* kvb = kvg + (size_t)bh * 196608;

    union { unsigned u[4]; bfrag v; } onesu;
    onesu.u[0] = 0x3F803F80u; onesu.u[1] = 0x3F803F80u;
    onesu.u[2] = 0x3F803F80u; onesu.u[3] = 0x3F803F80u;
    const bfrag ones = onesu.v;

    f4 o0 = {0.f, 0.f, 0.f, 0.f}, o1 = {0.f, 0.f, 0.f, 0.f};
    f4 l0 = {0.f, 0.f, 0.f, 0.f}, l1 = {0.f, 0.f, 0.f, 0.f};

    auto stage = [&](char* db, const char* gsrc) {
        stage16(db + w * 2048, gsrc + w * 2048 + lane * 16);
        stage16(db + w * 2048 + 1024, gsrc + w * 2048 + 1024 + lane * 16);
        stage16(db + 8192 + w * 1024, gsrc + 8192 + w * 1024 + lane * 16);
    };

    stage(kbuf[0], kvb);
    int cur = 0;
    for (int ch = 0; ch < 16; ++ch) {
        asm volatile("s_waitcnt vmcnt(0)" ::: "memory");
        __syncthreads();
        if (ch < 15) stage(kbuf[cur ^ 1], kvb + (size_t)(ch + 1) * 12288);
        const char* kb = kbuf[cur];
#pragma unroll
        for (int sub = 0; sub < 4; ++sub) {
            bfrag ka = *(const bfrag*)(kb + (2 * sub) * 1024 + lane * 16);
            bfrag kc2 = *(const bfrag*)(kb + (2 * sub + 1) * 1024 + lane * 16);
            bfrag vf = *(const bfrag*)(kb + 8192 + sub * 1024 + lane * 16);
            {   // q-frag 0
                f4 sa = {0.f, 0.f, 0.f, 0.f}, sb = {0.f, 0.f, 0.f, 0.f};
                sa = mfma_bf16(ka, qh0, sa);  sa = mfma_bf16(ka, ql0, sa);
                sb = mfma_bf16(kc2, qh0, sb); sb = mfma_bf16(kc2, ql0, sb);
                float ea[4], eb[4];
#pragma unroll
                for (int r = 0; r < 4; ++r) { ea[r] = fexp2(sa[r]); eb[r] = fexp2(sb[r]); }
#pragma unroll
                for (int r = 0; r < 4; ++r) plswap16(ea[r], eb[r]);
                union { unsigned u[4]; bfrag v; } pf;
                pf.u[0] = pk_trunc(ea[0], ea[1]); pf.u[1] = pk_trunc(ea[2], ea[3]);
                pf.u[2] = pk_trunc(eb[0], eb[1]); pf.u[3] = pk_trunc(eb[2], eb[3]);
                o0 = mfma_bf16(pf.v, vf, o0);
                l0 = mfma_bf16(pf.v, ones, l0);
            }
            {   // q-frag 1
                f4 sa = {0.f, 0.f, 0.f, 0.f}, sb = {0.f, 0.f, 0.f, 0.f};
                sa = mfma_bf16(ka, qh1, sa);  sa = mfma_bf16(ka, ql1, sa);
                sb = mfma_bf16(kc2, qh1, sb); sb = mfma_bf16(kc2, ql1, sb);
                float ea[4], eb[4];
#pragma unroll
                for (int r = 0; r < 4; ++r) { ea[r] = fexp2(sa[r]); eb[r] = fexp2(sb[r]); }
#pragma unroll
                for (int r = 0; r < 4; ++r) plswap16(ea[r], eb[r]);
                union { unsigned u[4]; bfrag v; } pf;
                pf.u[0] = pk_trunc(ea[0], ea[1]); pf.u[1] = pk_trunc(ea[2], ea[3]);
                pf.u[2] = pk_trunc(eb[0], eb[1]); pf.u[3] = pk_trunc(eb[2], eb[3]);
                o1 = mfma_bf16(pf.v, vf, o1);
                l1 = mfma_bf16(pf.v, ones, l1);
            }
        }
        cur ^= 1;
    }

    const int bbk = bh >> 3, h = bh & 7;
#pragma unroll
    for (int r = 0; r < 4; ++r) {
        int row = qd * 4 + r;
        xout[((size_t)(bbk * 2048 + q0 + row)) * 128 + h * 16 + c] = o0[r] / l0[r];
        xout[((size_t)(bbk * 2048 + q0 + 16 + row)) * 128 + h * 16 + c] = o1[r] / l1[r];
    }
}

// ---------- output projection (MFMA) ----------
// 256 blocks x 2 waves; wave-task = 16 seq rows x 128 outcols.
__global__ __launch_bounds__(128) void k_out(
    const float* __restrict__ x, const char* __restrict__ wimg,
    const float* __restrict__ bo, float* __restrict__ out)
{
    const int tid = threadIdx.x;
    const int w = tid >> 6, lane = tid & 63;
    const int n = lane & 15, qd = lane >> 4;
    const int row0 = (blockIdx.x * 2 + w) * 16;

    bfrag xh[4], xl[4];
#pragma unroll
    for (int kg = 0; kg < 4; ++kg)
        conv8(x + (size_t)(row0 + n) * 128 + kg * 32 + qd * 8, xh[kg], xl[kg]);

#pragma unroll
    for (int t = 0; t < 8; ++t) {
        float bv = bo[t * 16 + n];
        f4 cacc = {bv, bv, bv, bv};
#pragma unroll
        for (int kg = 0; kg < 4; ++kg) {
            const char* wb = wimg + 4 * 65536 + t * 8192 + kg * 2048;
            bfrag wh = *(const bfrag*)(wb + lane * 16);
            bfrag wl = *(const bfrag*)(wb + 1024 + lane * 16);
            cacc = mfma_bf16(xh[kg], wh, cacc);
            cacc = mfma_bf16(xl[kg], wh, cacc);
            cacc = mfma_bf16(xh[kg], wl, cacc);
        }
#pragma unroll
        for (int r = 0; r < 4; ++r)
            out[(size_t)(row0 + qd * 4 + r) * 128 + t * 16 + n] = cacc[r];
    }
}

extern "C" void kernel_launch(void* const* d_in, const int* in_sizes, int n_in,
                              void* d_out, int out_size, void* d_ws, size_t ws_size,
                              hipStream_t stream)
{
    const float* query = (const float*)d_in[0];
    const float* key   = (const float*)d_in[1];
    const float* value = (const float*)d_in[2];
    const float* pos   = (const float*)d_in[3];
    const float* W0 = (const float*)d_in[4];
    const float* b0 = (const float*)d_in[5];
    const float* W1 = (const float*)d_in[6];
    const float* b1 = (const float*)d_in[7];
    const float* W2 = (const float*)d_in[8];
    const float* b2 = (const float*)d_in[9];
    const float* Wo = (const float*)d_in[10];
    const float* bo = (const float*)d_in[11];

    char* ws = (char*)d_ws;
    char* qbuf = ws + WS_QB;
    char* kv   = ws + WS_KV;
    float* x   = (float*)(ws + WS_X);
    char* wimg = ws + WS_WI;
    float* out = (float*)d_out;

    w_prep<<<dim3(40), 256, 0, stream>>>(W0, W1, W2, Wo, wimg);
    k_proj<<<dim3(512), 256, 0, stream>>>(query, key, value, pos, b0, b1, b2,
                                          wimg, qbuf, kv);
    k_attn<<<dim3(16, 32), 256, 0, stream>>>(qbuf, kv, x);
    k_out<<<dim3(256), 128, 0, stream>>>(x, wimg, bo, out);
}

// Round 7
// 132.166 us; speedup vs baseline: 1.4450x; 1.0940x over previous
//
#include <hip/hip_runtime.h>
#include <math.h>

#define LOG2E 1.44269504088896340736f

typedef __attribute__((ext_vector_type(8))) short bfrag;   // 8 x bf16
typedef __attribute__((ext_vector_type(4))) float f4;
typedef unsigned __attribute__((ext_vector_type(2))) u2;

// ---------- helpers ----------
// D = (hi16(a)) | (hi16(b)<<16)  -- single v_perm_b32 where available
__device__ __forceinline__ unsigned pk_trunc(float a, float b) {
#if __has_builtin(__builtin_amdgcn_perm)
    return __builtin_amdgcn_perm(__float_as_uint(b), __float_as_uint(a), 0x07060302u);
#else
    return (__float_as_uint(a) >> 16) | (__float_as_uint(b) & 0xFFFF0000u);
#endif
}
__device__ __forceinline__ unsigned pk_rne(float a, float b) {
    unsigned ua = __float_as_uint(a); ua += 0x7FFFu + ((ua >> 16) & 1u);
    unsigned ub = __float_as_uint(b); ub += 0x7FFFu + ((ub >> 16) & 1u);
    return (ua >> 16) | (ub & 0xFFFF0000u);
}
__device__ __forceinline__ float trunchi(float x) {
    return __uint_as_float(__float_as_uint(x) & 0xFFFF0000u);
}
__device__ __forceinline__ float fexp2(float x) {
#if __has_builtin(__builtin_amdgcn_exp2f)
    return __builtin_amdgcn_exp2f(x);
#else
    return exp2f(x);
#endif
}
// exchange: a's odd 16-lane rows <-> b's even 16-lane rows (VALU pipe on gfx950)
__device__ __forceinline__ void plswap16(float& a, float& b) {
#if __has_builtin(__builtin_amdgcn_permlane16_swap)
    u2 t = __builtin_amdgcn_permlane16_swap(__float_as_uint(a), __float_as_uint(b),
                                            false, false);
    a = __uint_as_float(t.x); b = __uint_as_float(t.y);
#else
    bool odd = (threadIdx.x >> 4) & 1;
    float bs = __shfl_xor(b, 16, 64);
    float as = __shfl_xor(a, 16, 64);
    float na = odd ? bs : a;
    float nb = odd ? b : as;
    a = na; b = nb;
#endif
}
// async global->LDS, 16B/lane; lds base wave-uniform, HW lands lane i at base+i*16
__device__ __forceinline__ void stage16(void* lds_base, const void* g) {
#if __has_builtin(__builtin_amdgcn_global_load_lds)
    __builtin_amdgcn_global_load_lds(
        (const __attribute__((address_space(1))) unsigned int*)g,
        (__attribute__((address_space(3))) unsigned int*)lds_base, 16, 0, 0);
#else
    int lane = threadIdx.x & 63;
    *(float4*)((char*)lds_base + lane * 16) = *(const float4*)g;
#endif
}
__device__ __forceinline__ f4 mfma_bf16(bfrag a, bfrag b, f4 c) {
    return __builtin_amdgcn_mfma_f32_16x16x32_bf16(a, b, c, 0, 0, 0);
}
// split 8 consecutive fp32 at g into hi/lo bf16 fragment halves
__device__ __forceinline__ void conv8(const float* __restrict__ g, bfrag& hi, bfrag& lo) {
    f4 a = *(const f4*)g;
    f4 b = *(const f4*)(g + 4);
    union { unsigned u[4]; bfrag v; } H, L;
    H.u[0] = pk_trunc(a.x, a.y); H.u[1] = pk_trunc(a.z, a.w);
    H.u[2] = pk_trunc(b.x, b.y); H.u[3] = pk_trunc(b.z, b.w);
    L.u[0] = pk_trunc(a.x - trunchi(a.x), a.y - trunchi(a.y));
    L.u[1] = pk_trunc(a.z - trunchi(a.z), a.w - trunchi(a.w));
    L.u[2] = pk_trunc(b.x - trunchi(b.x), b.y - trunchi(b.y));
    L.u[3] = pk_trunc(b.z - trunchi(b.z), b.w - trunchi(b.w));
    hi = H.v; lo = L.v;
}
// q': C-tile-pair -> hi/lo frag image stores (plswap k-group map {0,2,1,3};
// applied consistently to q',k' so it cancels in S; matches P/V permutation).
__device__ __forceinline__ void store_q(f4 ea, f4 eb, char* base, int lodelta, int lane) {
    float eah[4], eal[4], ebh[4], ebl[4];
#pragma unroll
    for (int r = 0; r < 4; ++r) {
        eah[r] = trunchi(ea[r]); eal[r] = ea[r] - eah[r];
        ebh[r] = trunchi(eb[r]); ebl[r] = eb[r] - ebh[r];
    }
#pragma unroll
    for (int r = 0; r < 4; ++r) { plswap16(eah[r], ebh[r]); plswap16(eal[r], ebl[r]); }
    union { unsigned u[4]; bfrag v; } H, L;
    H.u[0] = pk_trunc(eah[0], eah[1]); H.u[1] = pk_trunc(eah[2], eah[3]);
    H.u[2] = pk_trunc(ebh[0], ebh[1]); H.u[3] = pk_trunc(ebh[2], ebh[3]);
    L.u[0] = pk_trunc(eal[0], eal[1]); L.u[1] = pk_trunc(eal[2], eal[3]);
    L.u[2] = pk_trunc(ebl[0], ebl[1]); L.u[3] = pk_trunc(ebl[2], ebl[3]);
    *(bfrag*)(base + lane * 16) = H.v;
    *(bfrag*)(base + lodelta + lane * 16) = L.v;
}
// k'/v: C-tile-pair -> single RNE bf16 frag store
__device__ __forceinline__ void store_rne(f4 ea, f4 eb, char* base, int lane) {
    float a[4], b[4];
#pragma unroll
    for (int r = 0; r < 4; ++r) { a[r] = ea[r]; b[r] = eb[r]; }
#pragma unroll
    for (int r = 0; r < 4; ++r) plswap16(a[r], b[r]);
    union { unsigned u[4]; bfrag v; } P;
    P.u[0] = pk_rne(a[0], a[1]); P.u[1] = pk_rne(a[2], a[3]);
    P.u[2] = pk_rne(b[0], b[1]); P.u[3] = pk_rne(b[2], b[3]);
    *(bfrag*)(base + lane * 16) = P.v;
}

// ---------- workspace byte offsets ----------
// qb:   [bh][128 panels][hi 1KB | lo 1KB]            = 8,388,608
// kv:   [bh][16 chunks][k 8KB | vt 4KB]  (128 keys)  = 6,291,456
// x:    [B][S][128] fp32                             = 4,194,304
// wimg: 5 x [8 tiles][4 kg][hi 1KB|lo 1KB]           = 327,680
#define WS_QB 0u
#define WS_KV 8388608u
#define WS_X  14680064u
#define WS_WI 18874368u

// ---------- weight fragment prep ----------
// img: 0 = 0.25*log2e*W0, 1 = log2e*W0, 2 = W1, 3 = W2, 4 = Wo.
__global__ __launch_bounds__(256) void w_prep(
    const float* __restrict__ W0, const float* __restrict__ W1,
    const float* __restrict__ W2, const float* __restrict__ Wo,
    char* __restrict__ wimg)
{
    int wid = blockIdx.x * 4 + (threadIdx.x >> 6);   // 0..159
    int lane = threadIdx.x & 63;
    int img = wid >> 5, rem = wid & 31, tile = rem >> 2, kg = rem & 3;
    const float* W = (img <= 1) ? W0 : (img == 2) ? W1 : (img == 3) ? W2 : Wo;
    float s = (img == 0) ? 0.25f * LOG2E : (img == 1) ? LOG2E : 1.0f;
    int n = lane & 15, qd = lane >> 4;
    const float* g = W + (size_t)(tile * 16 + n) * 128 + kg * 32 + qd * 8;
    f4 a = *(const f4*)g, b = *(const f4*)(g + 4);
    a.x *= s; a.y *= s; a.z *= s; a.w *= s;
    b.x *= s; b.y *= s; b.z *= s; b.w *= s;
    union { unsigned u[4]; bfrag v; } H, L;
    H.u[0] = pk_trunc(a.x, a.y); H.u[1] = pk_trunc(a.z, a.w);
    H.u[2] = pk_trunc(b.x, b.y); H.u[3] = pk_trunc(b.z, b.w);
    L.u[0] = pk_trunc(a.x - trunchi(a.x), a.y - trunchi(a.y));
    L.u[1] = pk_trunc(a.z - trunchi(a.z), a.w - trunchi(a.w));
    L.u[2] = pk_trunc(b.x - trunchi(b.x), b.y - trunchi(b.y));
    L.u[3] = pk_trunc(b.z - trunchi(b.z), b.w - trunchi(b.w));
    char* dst = wimg + img * 65536 + tile * 8192 + kg * 2048;
    *(bfrag*)(dst + lane * 16) = H.v;
    *(bfrag*)(dst + 1024 + lane * 16) = L.v;
}

// ---------- MFMA projections (input-shared) ----------
// Block = 256 thr, 32 seq rows (2 panels) x ALL 8 heads, one batch b.
// Grid 256 = (4 b x 64 s32). Phase 0: stage+convert X (q,k,v,p) once into
// 64 KB LDS in MFMA fragment layout (hi/lo). Phase 1: wave w handles heads
// {2w, 2w+1}; per head Q/K transposed GEMMs (A = W-frag image from global
// L2, B = X-frag from LDS) and V normal GEMM (A = X-frag, B = W2-frag).
// Kills the 8x per-head input re-read and 8x conversion VALU of R6.
__global__ __launch_bounds__(256) void k_proj(
    const float* __restrict__ query, const float* __restrict__ key,
    const float* __restrict__ value, const float* __restrict__ pos,
    const float* __restrict__ b0, const float* __restrict__ b1,
    const float* __restrict__ b2,
    const char* __restrict__ wimg, char* __restrict__ qb, char* __restrict__ kv)
{
    __shared__ __align__(16) char xlds[65536];   // [arr 4][panel 2][kg 4][hi 1K|lo 1K]
    const int tid = threadIdx.x;
    const int bid = blockIdx.x;
    const int b = bid >> 6, s32 = bid & 63;
    const size_t rowbase = (size_t)(b * 2048 + s32 * 32);

    // ---- phase 0: stage + convert ----
#pragma unroll
    for (int i = 0; i < 8; ++i) {
        int cid = tid + i * 256;                 // 0..2047
        int arr = cid >> 9, rem = cid & 511;
        int c32 = rem >> 4, u = rem & 15;        // row-in-block, dim-chunk
        const float* sp = (arr == 0) ? query : (arr == 1) ? key
                        : (arr == 2) ? value : pos;     // wave-uniform per i
        bfrag hi, lo;
        conv8(sp + (rowbase + c32) * 128 + u * 8, hi, lo);
        int base = arr * 16384 + (c32 >> 4) * 8192 + (u >> 2) * 2048
                 + ((u & 3) * 16 + (c32 & 15)) * 16;
        *(bfrag*)(xlds + base) = hi;
        *(bfrag*)(xlds + base + 1024) = lo;
    }
    __syncthreads();

    // ---- phase 1: per-head GEMMs ----
    const int w = tid >> 6, lane = tid & 63;
    const int n = lane & 15, qd = lane >> 4;
#pragma unroll
    for (int hh = 0; hh < 2; ++hh) {
        const int h = w * 2 + hh;
        const int bh = b * 8 + h;
        // -- Q: q' = [0.25L*(query W0^T + b0) || L*(pos W0^T + b0)] --
        {
            bfrag wqh[4], wql[4], wph[4], wpl[4];
#pragma unroll
            for (int kg = 0; kg < 4; ++kg) {
                const char* wb = wimg + 0 * 65536 + h * 8192 + kg * 2048;
                wqh[kg] = *(const bfrag*)(wb + lane * 16);
                wql[kg] = *(const bfrag*)(wb + 1024 + lane * 16);
                const char* pb = wimg + 1 * 65536 + h * 8192 + kg * 2048;
                wph[kg] = *(const bfrag*)(pb + lane * 16);
                wpl[kg] = *(const bfrag*)(pb + 1024 + lane * 16);
            }
            float bq[4], bp[4];
#pragma unroll
            for (int r = 0; r < 4; ++r) {
                float bv = b0[h * 16 + qd * 4 + r];
                bq[r] = 0.25f * LOG2E * bv; bp[r] = LOG2E * bv;
            }
#pragma unroll
            for (int pp = 0; pp < 2; ++pp) {
                f4 cq = {bq[0], bq[1], bq[2], bq[3]};
                f4 cp = {bp[0], bp[1], bp[2], bp[3]};
#pragma unroll
                for (int kg = 0; kg < 4; ++kg) {
                    const char* xq = xlds + 0 * 16384 + pp * 8192 + kg * 2048 + lane * 16;
                    const char* xp = xlds + 3 * 16384 + pp * 8192 + kg * 2048 + lane * 16;
                    bfrag xh = *(const bfrag*)xq, xl = *(const bfrag*)(xq + 1024);
                    bfrag ph = *(const bfrag*)xp, pl = *(const bfrag*)(xp + 1024);
                    cq = mfma_bf16(wqh[kg], xh, cq);
                    cq = mfma_bf16(wqh[kg], xl, cq);
                    cq = mfma_bf16(wql[kg], xh, cq);
                    cp = mfma_bf16(wph[kg], ph, cp);
                    cp = mfma_bf16(wph[kg], pl, cp);
                    cp = mfma_bf16(wpl[kg], ph, cp);
                }
                int pg = s32 * 2 + pp;
                store_q(cq, cp, qb + (size_t)bh * 262144 + (size_t)pg * 2048, 1024, lane);
            }
        }
        // -- K: k' = [(key W1^T + b1) || (pos W1^T + b1)], RNE bf16 --
        {
            bfrag w1h[4], w1l[4];
#pragma unroll
            for (int kg = 0; kg < 4; ++kg) {
                const char* wb = wimg + 2 * 65536 + h * 8192 + kg * 2048;
                w1h[kg] = *(const bfrag*)(wb + lane * 16);
                w1l[kg] = *(const bfrag*)(wb + 1024 + lane * 16);
            }
            float bk[4];
#pragma unroll
            for (int r = 0; r < 4; ++r) bk[r] = b1[h * 16 + qd * 4 + r];
#pragma unroll
            for (int pp = 0; pp < 2; ++pp) {
                f4 ck = {bk[0], bk[1], bk[2], bk[3]};
                f4 cpk = {bk[0], bk[1], bk[2], bk[3]};
#pragma unroll
                for (int kg = 0; kg < 4; ++kg) {
                    const char* xk = xlds + 1 * 16384 + pp * 8192 + kg * 2048 + lane * 16;
                    const char* xp = xlds + 3 * 16384 + pp * 8192 + kg * 2048 + lane * 16;
                    bfrag xh = *(const bfrag*)xk, xl = *(const bfrag*)(xk + 1024);
                    bfrag ph = *(const bfrag*)xp, pl = *(const bfrag*)(xp + 1024);
                    ck = mfma_bf16(w1h[kg], xh, ck);
                    ck = mfma_bf16(w1h[kg], xl, ck);
                    ck = mfma_bf16(w1l[kg], xh, ck);
                    cpk = mfma_bf16(w1h[kg], ph, cpk);
                    cpk = mfma_bf16(w1h[kg], pl, cpk);
                    cpk = mfma_bf16(w1l[kg], ph, cpk);
                }
                int pg = s32 * 2 + pp;
                store_rne(ck, cpk,
                          kv + (size_t)bh * 196608 + (size_t)(pg >> 3) * 12288
                          + (pg & 7) * 1024, lane);
            }
        }
        // -- V: vt = value W2^T + b2 (normal orientation, RNE bf16) --
        {
            bfrag w2h[4], w2l[4];
#pragma unroll
            for (int kg = 0; kg < 4; ++kg) {
                const char* wb = wimg + 3 * 65536 + h * 8192 + kg * 2048;
                w2h[kg] = *(const bfrag*)(wb + lane * 16);
                w2l[kg] = *(const bfrag*)(wb + 1024 + lane * 16);
            }
            float bv = b2[h * 16 + n];
            f4 ca = {bv, bv, bv, bv};
            f4 cb = {bv, bv, bv, bv};
#pragma unroll
            for (int pp = 0; pp < 2; ++pp) {
#pragma unroll
                for (int kg = 0; kg < 4; ++kg) {
                    const char* xv = xlds + 2 * 16384 + pp * 8192 + kg * 2048 + lane * 16;
                    bfrag ah = *(const bfrag*)xv, al = *(const bfrag*)(xv + 1024);
                    if (pp == 0) {
                        ca = mfma_bf16(ah, w2h[kg], ca);
                        ca = mfma_bf16(al, w2h[kg], ca);
                        ca = mfma_bf16(ah, w2l[kg], ca);
                    } else {
                        cb = mfma_bf16(ah, w2h[kg], cb);
                        cb = mfma_bf16(al, w2h[kg], cb);
                        cb = mfma_bf16(ah, w2l[kg], cb);
                    }
                }
            }
            store_rne(ca, cb,
                      kv + (size_t)bh * 196608 + (size_t)(s32 >> 2) * 12288
                      + 8192 + (s32 & 3) * 1024, lane);
        }
    }
}

// ---------- fused flash attention ----------
// Block = 4 waves x 32 q-rows; grid (16, 32 bh). Per 128-key chunk: stage
// 12KB [k 8K | vt 4K] double-buffered (explicit vmcnt(0) drain before the
// barrier — correctness-critical, see R3/R4); per 32-key sub: S^T = k(A) x
// q'hi/lo(B) 2 MFMAs/panel; exp2; C->A via plswap (key-permuted, matches vt);
// PV MFMA + ones-MFMA row-sum (consistent with truncated P). No online max.
__global__ __launch_bounds__(256) void k_attn(
    const char* __restrict__ qb, const char* __restrict__ kvg,
    float* __restrict__ xout)
{
    __shared__ __align__(16) char kbuf[2][12288];
    const int tid = threadIdx.x;
    const int w = tid >> 6, lane = tid & 63;
    const int c = lane & 15, qd = lane >> 4;
    const int bh = blockIdx.y;
    const int q0 = blockIdx.x * 128 + w * 32;

    const char* qpb = qb + (size_t)bh * 262144 + (size_t)(q0 >> 4) * 2048;
    bfrag qh0 = *(const bfrag*)(qpb + lane * 16);
    bfrag ql0 = *(const bfrag*)(qpb + 1024 + lane * 16);
    bfrag qh1 = *(const bfrag*)(qpb + 2048 + lane * 16);
    bfrag ql1 = *(const bfrag*)(qpb + 3072 + lane * 16);

    const char* kvb = kvg + (size_t)bh * 196608;

    union { unsigned u[4]; bfrag v; } onesu;
    onesu.u[0] = 0x3F803F80u; onesu.u[1] = 0x3F803F80u;
    onesu.u[2] = 0x3F803F80u; onesu.u[3] = 0x3F803F80u;
    const bfrag ones = onesu.v;

    f4 o0 = {0.f, 0.f, 0.f, 0.f}, o1 = {0.f, 0.f, 0.f, 0.f};
    f4 l0 = {0.f, 0.f, 0.f, 0.f}, l1 = {0.f, 0.f, 0.f, 0.f};

    auto stage = [&](char* db, const char* gsrc) {
        stage16(db + w * 2048, gsrc + w * 2048 + lane * 16);
        stage16(db + w * 2048 + 1024, gsrc + w * 2048 + 1024 + lane * 16);
        stage16(db + 8192 + w * 1024, gsrc + 8192 + w * 1024 + lane * 16);
    };

    stage(kbuf[0], kvb);
    const char* gnext = kvb + 12288;
    int cur = 0;
    for (int ch = 0; ch < 16; ++ch) {
        asm volatile("s_waitcnt vmcnt(0)" ::: "memory");
        __syncthreads();
        if (ch < 15) { stage(kbuf[cur ^ 1], gnext); gnext += 12288; }
        const char* kb = kbuf[cur];
#pragma unroll
        for (int sub = 0; sub < 4; ++sub) {
            bfrag ka = *(const bfrag*)(kb + (2 * sub) * 1024 + lane * 16);
            bfrag kc2 = *(const bfrag*)(kb + (2 * sub + 1) * 1024 + lane * 16);
            bfrag vf = *(const bfrag*)(kb + 8192 + sub * 1024 + lane * 16);
            {   // q-frag 0
                f4 sa = {0.f, 0.f, 0.f, 0.f}, sb = {0.f, 0.f, 0.f, 0.f};
                sa = mfma_bf16(ka, qh0, sa);  sa = mfma_bf16(ka, ql0, sa);
                sb = mfma_bf16(kc2, qh0, sb); sb = mfma_bf16(kc2, ql0, sb);
                float ea[4], eb[4];
#pragma unroll
                for (int r = 0; r < 4; ++r) { ea[r] = fexp2(sa[r]); eb[r] = fexp2(sb[r]); }
#pragma unroll
                for (int r = 0; r < 4; ++r) plswap16(ea[r], eb[r]);
                union { unsigned u[4]; bfrag v; } pf;
                pf.u[0] = pk_trunc(ea[0], ea[1]); pf.u[1] = pk_trunc(ea[2], ea[3]);
                pf.u[2] = pk_trunc(eb[0], eb[1]); pf.u[3] = pk_trunc(eb[2], eb[3]);
                o0 = mfma_bf16(pf.v, vf, o0);
                l0 = mfma_bf16(pf.v, ones, l0);
            }
            {   // q-frag 1
                f4 sa = {0.f, 0.f, 0.f, 0.f}, sb = {0.f, 0.f, 0.f, 0.f};
                sa = mfma_bf16(ka, qh1, sa);  sa = mfma_bf16(ka, ql1, sa);
                sb = mfma_bf16(kc2, qh1, sb); sb = mfma_bf16(kc2, ql1, sb);
                float ea[4], eb[4];
#pragma unroll
                for (int r = 0; r < 4; ++r) { ea[r] = fexp2(sa[r]); eb[r] = fexp2(sb[r]); }
#pragma unroll
                for (int r = 0; r < 4; ++r) plswap16(ea[r], eb[r]);
                union { unsigned u[4]; bfrag v; } pf;
                pf.u[0] = pk_trunc(ea[0], ea[1]); pf.u[1] = pk_trunc(ea[2], ea[3]);
                pf.u[2] = pk_trunc(eb[0], eb[1]); pf.u[3] = pk_trunc(eb[2], eb[3]);
                o1 = mfma_bf16(pf.v, vf, o1);
                l1 = mfma_bf16(pf.v, ones, l1);
            }
        }
        cur ^= 1;
    }

    const int bbk = bh >> 3, h = bh & 7;
#pragma unroll
    for (int r = 0; r < 4; ++r) {
        int row = qd * 4 + r;
        xout[((size_t)(bbk * 2048 + q0 + row)) * 128 + h * 16 + c] = o0[r] / l0[r];
        xout[((size_t)(bbk * 2048 + q0 + 16 + row)) * 128 + h * 16 + c] = o1[r] / l1[r];
    }
}

// ---------- output projection (MFMA) ----------
// 512 blocks x 2 waves; wave-task = 16 seq rows x 4 of 8 col-tiles.
__global__ __launch_bounds__(128) void k_out(
    const float* __restrict__ x, const char* __restrict__ wimg,
    const float* __restrict__ bo, float* __restrict__ out)
{
    const int tid = threadIdx.x;
    const int w = tid >> 6, lane = tid & 63;
    const int n = lane & 15, qd = lane >> 4;
    const int row0 = blockIdx.x * 16;

    bfrag xh[4], xl[4];
#pragma unroll
    for (int kg = 0; kg < 4; ++kg)
        conv8(x + (size_t)(row0 + n) * 128 + kg * 32 + qd * 8, xh[kg], xl[kg]);

#pragma unroll
    for (int tt = 0; tt < 4; ++tt) {
        int t = w * 4 + tt;
        float bv = bo[t * 16 + n];
        f4 cacc = {bv, bv, bv, bv};
#pragma unroll
        for (int kg = 0; kg < 4; ++kg) {
            const char* wb = wimg + 4 * 65536 + t * 8192 + kg * 2048;
            bfrag wh = *(const bfrag*)(wb + lane * 16);
            bfrag wl = *(const bfrag*)(wb + 1024 + lane * 16);
            cacc = mfma_bf16(xh[kg], wh, cacc);
            cacc = mfma_bf16(xl[kg], wh, cacc);
            cacc = mfma_bf16(xh[kg], wl, cacc);
        }
#pragma unroll
        for (int r = 0; r < 4; ++r)
            out[(size_t)(row0 + qd * 4 + r) * 128 + t * 16 + n] = cacc[r];
    }
}

extern "C" void kernel_launch(void* const* d_in, const int* in_sizes, int n_in,
                              void* d_out, int out_size, void* d_ws, size_t ws_size,
                              hipStream_t stream)
{
    const float* query = (const float*)d_in[0];
    const float* key   = (const float*)d_in[1];
    const float* value = (const float*)d_in[2];
    const float* pos   = (const float*)d_in[3];
    const float* W0 = (const float*)d_in[4];
    const float* b0 = (const float*)d_in[5];
    const float* W1 = (const float*)d_in[6];
    const float* b1 = (const float*)d_in[7];
    const float* W2 = (const float*)d_in[8];
    const float* b2 = (const float*)d_in[9];
    const float* Wo = (const float*)d_in[10];
    const float* bo = (const float*)d_in[11];

    char* ws = (char*)d_ws;
    char* qbuf = ws + WS_QB;
    char* kv   = ws + WS_KV;
    float* x   = (float*)(ws + WS_X);
    char* wimg = ws + WS_WI;
    float* out = (float*)d_out;

    w_prep<<<dim3(40), 256, 0, stream>>>(W0, W1, W2, Wo, wimg);
    k_proj<<<dim3(256), 256, 0, stream>>>(query, key, value, pos, b0, b1, b2,
                                          wimg, qbuf, kv);
    k_attn<<<dim3(16, 32), 256, 0, stream>>>(qbuf, kv, x);
    k_out<<<dim3(512), 128, 0, stream>>>(x, wimg, bo, out);
}

// Round 8
// 128.564 us; speedup vs baseline: 1.4855x; 1.0280x over previous
//
#include <hip/hip_runtime.h>
#include <math.h>

#define LOG2E 1.44269504088896340736f

typedef __attribute__((ext_vector_type(8))) short bfrag;   // 8 x bf16
typedef __attribute__((ext_vector_type(4))) float f4;
typedef unsigned __attribute__((ext_vector_type(2))) u2;

// ---------- helpers ----------
// D = (hi16(a)) | (hi16(b)<<16)  -- single v_perm_b32 where available
__device__ __forceinline__ unsigned pk_trunc(float a, float b) {
#if __has_builtin(__builtin_amdgcn_perm)
    return __builtin_amdgcn_perm(__float_as_uint(b), __float_as_uint(a), 0x07060302u);
#else
    return (__float_as_uint(a) >> 16) | (__float_as_uint(b) & 0xFFFF0000u);
#endif
}
__device__ __forceinline__ unsigned pk_rne(float a, float b) {
    unsigned ua = __float_as_uint(a); ua += 0x7FFFu + ((ua >> 16) & 1u);
    unsigned ub = __float_as_uint(b); ub += 0x7FFFu + ((ub >> 16) & 1u);
    return (ua >> 16) | (ub & 0xFFFF0000u);
}
__device__ __forceinline__ float trunchi(float x) {
    return __uint_as_float(__float_as_uint(x) & 0xFFFF0000u);
}
__device__ __forceinline__ float fexp2(float x) {
#if __has_builtin(__builtin_amdgcn_exp2f)
    return __builtin_amdgcn_exp2f(x);
#else
    return exp2f(x);
#endif
}
// async global->LDS, 16B/lane; lds base wave-uniform, HW lands lane i at base+i*16
__device__ __forceinline__ void stage16(void* lds_base, const void* g) {
#if __has_builtin(__builtin_amdgcn_global_load_lds)
    __builtin_amdgcn_global_load_lds(
        (const __attribute__((address_space(1))) unsigned int*)g,
        (__attribute__((address_space(3))) unsigned int*)lds_base, 16, 0, 0);
#else
    int lane = threadIdx.x & 63;
    *(float4*)((char*)lds_base + lane * 16) = *(const float4*)g;
#endif
}
__device__ __forceinline__ f4 mfma_bf16(bfrag a, bfrag b, f4 c) {
    return __builtin_amdgcn_mfma_f32_16x16x32_bf16(a, b, c, 0, 0, 0);
}
// split 8 consecutive fp32 at g into hi/lo bf16 fragment halves
__device__ __forceinline__ void conv8(const float* __restrict__ g, bfrag& hi, bfrag& lo) {
    f4 a = *(const f4*)g;
    f4 b = *(const f4*)(g + 4);
    union { unsigned u[4]; bfrag v; } H, L;
    H.u[0] = pk_trunc(a.x, a.y); H.u[1] = pk_trunc(a.z, a.w);
    H.u[2] = pk_trunc(b.x, b.y); H.u[3] = pk_trunc(b.z, b.w);
    L.u[0] = pk_trunc(a.x - trunchi(a.x), a.y - trunchi(a.y));
    L.u[1] = pk_trunc(a.z - trunchi(a.z), a.w - trunchi(a.w));
    L.u[2] = pk_trunc(b.x - trunchi(b.x), b.y - trunchi(b.y));
    L.u[3] = pk_trunc(b.z - trunchi(b.z), b.w - trunchi(b.w));
    hi = H.v; lo = L.v;
}
// DIRECT packing (no cross-lane): frag k-positions j0..3 = ea regs, j4..7 = eb
// regs. The implied k-permutation sigma(quad,j) is baked consistently into
// BOTH MFMA operands everywhere (q'&k' for S; vt tau for PV; Wo pi for out),
// so it cancels in every reduction.
__device__ __forceinline__ void store_q2(f4 ea, f4 eb, char* base, int lodelta, int lane) {
    union { unsigned u[4]; bfrag v; } H, L;
    H.u[0] = pk_trunc(ea[0], ea[1]); H.u[1] = pk_trunc(ea[2], ea[3]);
    H.u[2] = pk_trunc(eb[0], eb[1]); H.u[3] = pk_trunc(eb[2], eb[3]);
    L.u[0] = pk_trunc(ea[0] - trunchi(ea[0]), ea[1] - trunchi(ea[1]));
    L.u[1] = pk_trunc(ea[2] - trunchi(ea[2]), ea[3] - trunchi(ea[3]));
    L.u[2] = pk_trunc(eb[0] - trunchi(eb[0]), eb[1] - trunchi(eb[1]));
    L.u[3] = pk_trunc(eb[2] - trunchi(eb[2]), eb[3] - trunchi(eb[3]));
    *(bfrag*)(base + lane * 16) = H.v;
    *(bfrag*)(base + lodelta + lane * 16) = L.v;
}
__device__ __forceinline__ void store_rne2(f4 ea, f4 eb, char* base, int lane) {
    union { unsigned u[4]; bfrag v; } P;
    P.u[0] = pk_rne(ea[0], ea[1]); P.u[1] = pk_rne(ea[2], ea[3]);
    P.u[2] = pk_rne(eb[0], eb[1]); P.u[3] = pk_rne(eb[2], eb[3]);
    *(bfrag*)(base + lane * 16) = P.v;
}

// ---------- workspace byte offsets ----------
// qb:   [bh][128 panels][hi 1KB | lo 1KB]            = 8,388,608
// kv:   [bh][16 chunks][k 8KB | vt 4KB]  (128 keys)  = 6,291,456
// x:    [512 panels][kg 4][64 lanes][16B] bf16       = 2,097,152
// wimg: 5 x [8 tiles][4 kg][hi 1KB|lo 1KB]           = 327,680
#define WS_QB 0u
#define WS_KV 8388608u
#define WS_X  14680064u
#define WS_WI 18874368u

// ---------- weight fragment prep ----------
// img: 0 = 0.25*log2e*W0, 1 = log2e*W0, 2 = W1, 3 = W2, 4 = Wo.
// img 0-3: standard layout (quad holds 8 contiguous indims).
// img 4: pi layout (quad holds [4 dims of even head-half | 4 of odd half])
// matching k_attn's x-frag write order.
__global__ __launch_bounds__(256) void w_prep(
    const float* __restrict__ W0, const float* __restrict__ W1,
    const float* __restrict__ W2, const float* __restrict__ Wo,
    char* __restrict__ wimg)
{
    int wid = blockIdx.x * 4 + (threadIdx.x >> 6);   // 0..159
    int lane = threadIdx.x & 63;
    int img = wid >> 5, rem = wid & 31, tile = rem >> 2, kg = rem & 3;
    const float* W = (img <= 1) ? W0 : (img == 2) ? W1 : (img == 3) ? W2 : Wo;
    float s = (img == 0) ? 0.25f * LOG2E : (img == 1) ? LOG2E : 1.0f;
    int n = lane & 15, qd = lane >> 4;
    const float* rowp = W + (size_t)(tile * 16 + n) * 128 + kg * 32;
    f4 a, b;
    if (img == 4) { a = *(const f4*)(rowp + qd * 4); b = *(const f4*)(rowp + 16 + qd * 4); }
    else          { a = *(const f4*)(rowp + qd * 8); b = *(const f4*)(rowp + qd * 8 + 4); }
    a.x *= s; a.y *= s; a.z *= s; a.w *= s;
    b.x *= s; b.y *= s; b.z *= s; b.w *= s;
    union { unsigned u[4]; bfrag v; } H, L;
    H.u[0] = pk_trunc(a.x, a.y); H.u[1] = pk_trunc(a.z, a.w);
    H.u[2] = pk_trunc(b.x, b.y); H.u[3] = pk_trunc(b.z, b.w);
    L.u[0] = pk_trunc(a.x - trunchi(a.x), a.y - trunchi(a.y));
    L.u[1] = pk_trunc(a.z - trunchi(a.z), a.w - trunchi(a.w));
    L.u[2] = pk_trunc(b.x - trunchi(b.x), b.y - trunchi(b.y));
    L.u[3] = pk_trunc(b.z - trunchi(b.z), b.w - trunchi(b.w));
    char* dst = wimg + img * 65536 + tile * 8192 + kg * 2048;
    *(bfrag*)(dst + lane * 16) = H.v;
    *(bfrag*)(dst + 1024 + lane * 16) = L.v;
}

// ---------- MFMA projections (input-shared) ----------
// Block = 256 thr, 32 seq rows x ALL 8 heads, one batch. Phase 0: stage+
// convert X once into 64 KB LDS (frag layout, hi/lo). Phase 1: wave w does
// heads {2w,2w+1}: Q/K transposed GEMMs C[dim][seq], V normal C[key][dim];
// all outputs stored with DIRECT packing (sigma/tau baked, no plswap).
__global__ __launch_bounds__(256) void k_proj(
    const float* __restrict__ query, const float* __restrict__ key,
    const float* __restrict__ value, const float* __restrict__ pos,
    const float* __restrict__ b0, const float* __restrict__ b1,
    const float* __restrict__ b2,
    const char* __restrict__ wimg, char* __restrict__ qb, char* __restrict__ kv)
{
    __shared__ __align__(16) char xlds[65536];   // [arr 4][panel 2][kg 4][hi 1K|lo 1K]
    const int tid = threadIdx.x;
    const int bid = blockIdx.x;
    const int b = bid >> 6, s32 = bid & 63;
    const size_t rowbase = (size_t)(b * 2048 + s32 * 32);

    // ---- phase 0: stage + convert ----
#pragma unroll
    for (int i = 0; i < 8; ++i) {
        int cid = tid + i * 256;                 // 0..2047
        int arr = cid >> 9, rem = cid & 511;
        int c32 = rem >> 4, u = rem & 15;        // row-in-block, dim-chunk
        const float* sp = (arr == 0) ? query : (arr == 1) ? key
                        : (arr == 2) ? value : pos;     // wave-uniform per i
        bfrag hi, lo;
        conv8(sp + (rowbase + c32) * 128 + u * 8, hi, lo);
        int base = arr * 16384 + (c32 >> 4) * 8192 + (u >> 2) * 2048
                 + ((u & 3) * 16 + (c32 & 15)) * 16;
        *(bfrag*)(xlds + base) = hi;
        *(bfrag*)(xlds + base + 1024) = lo;
    }
    __syncthreads();

    // ---- phase 1: per-head GEMMs ----
    const int w = tid >> 6, lane = tid & 63;
    const int n = lane & 15, qd = lane >> 4;
#pragma unroll
    for (int hh = 0; hh < 2; ++hh) {
        const int h = w * 2 + hh;
        const int bh = b * 8 + h;
        // -- Q: q' = [0.25L*(query W0^T + b0) || L*(pos W0^T + b0)] --
        {
            bfrag wqh[4], wql[4], wph[4], wpl[4];
#pragma unroll
            for (int kg = 0; kg < 4; ++kg) {
                const char* wb = wimg + 0 * 65536 + h * 8192 + kg * 2048;
                wqh[kg] = *(const bfrag*)(wb + lane * 16);
                wql[kg] = *(const bfrag*)(wb + 1024 + lane * 16);
                const char* pb = wimg + 1 * 65536 + h * 8192 + kg * 2048;
                wph[kg] = *(const bfrag*)(pb + lane * 16);
                wpl[kg] = *(const bfrag*)(pb + 1024 + lane * 16);
            }
            float bq[4], bp[4];
#pragma unroll
            for (int r = 0; r < 4; ++r) {
                float bv = b0[h * 16 + qd * 4 + r];
                bq[r] = 0.25f * LOG2E * bv; bp[r] = LOG2E * bv;
            }
#pragma unroll
            for (int pp = 0; pp < 2; ++pp) {
                f4 cq = {bq[0], bq[1], bq[2], bq[3]};
                f4 cp = {bp[0], bp[1], bp[2], bp[3]};
#pragma unroll
                for (int kg = 0; kg < 4; ++kg) {
                    const char* xq = xlds + 0 * 16384 + pp * 8192 + kg * 2048 + lane * 16;
                    const char* xp = xlds + 3 * 16384 + pp * 8192 + kg * 2048 + lane * 16;
                    bfrag xh = *(const bfrag*)xq, xl = *(const bfrag*)(xq + 1024);
                    bfrag ph = *(const bfrag*)xp, pl = *(const bfrag*)(xp + 1024);
                    cq = mfma_bf16(wqh[kg], xh, cq);
                    cq = mfma_bf16(wqh[kg], xl, cq);
                    cq = mfma_bf16(wql[kg], xh, cq);
                    cp = mfma_bf16(wph[kg], ph, cp);
                    cp = mfma_bf16(wph[kg], pl, cp);
                    cp = mfma_bf16(wpl[kg], ph, cp);
                }
                int pg = s32 * 2 + pp;
                store_q2(cq, cp, qb + (size_t)bh * 262144 + (size_t)pg * 2048, 1024, lane);
            }
        }
        // -- K: k' = [(key W1^T + b1) || (pos W1^T + b1)], RNE bf16 --
        {
            bfrag w1h[4], w1l[4];
#pragma unroll
            for (int kg = 0; kg < 4; ++kg) {
                const char* wb = wimg + 2 * 65536 + h * 8192 + kg * 2048;
                w1h[kg] = *(const bfrag*)(wb + lane * 16);
                w1l[kg] = *(const bfrag*)(wb + 1024 + lane * 16);
            }
            float bk[4];
#pragma unroll
            for (int r = 0; r < 4; ++r) bk[r] = b1[h * 16 + qd * 4 + r];
#pragma unroll
            for (int pp = 0; pp < 2; ++pp) {
                f4 ck = {bk[0], bk[1], bk[2], bk[3]};
                f4 cpk = {bk[0], bk[1], bk[2], bk[3]};
#pragma unroll
                for (int kg = 0; kg < 4; ++kg) {
                    const char* xk = xlds + 1 * 16384 + pp * 8192 + kg * 2048 + lane * 16;
                    const char* xp = xlds + 3 * 16384 + pp * 8192 + kg * 2048 + lane * 16;
                    bfrag xh = *(const bfrag*)xk, xl = *(const bfrag*)(xk + 1024);
                    bfrag ph = *(const bfrag*)xp, pl = *(const bfrag*)(xp + 1024);
                    ck = mfma_bf16(w1h[kg], xh, ck);
                    ck = mfma_bf16(w1h[kg], xl, ck);
                    ck = mfma_bf16(w1l[kg], xh, ck);
                    cpk = mfma_bf16(w1h[kg], ph, cpk);
                    cpk = mfma_bf16(w1h[kg], pl, cpk);
                    cpk = mfma_bf16(w1l[kg], ph, cpk);
                }
                int pg = s32 * 2 + pp;
                store_rne2(ck, cpk,
                           kv + (size_t)bh * 196608 + (size_t)(pg >> 3) * 12288
                           + (pg & 7) * 1024, lane);
            }
        }
        // -- V: vt = value W2^T + b2 (normal orientation, tau packing) --
        {
            bfrag w2h[4], w2l[4];
#pragma unroll
            for (int kg = 0; kg < 4; ++kg) {
                const char* wb = wimg + 3 * 65536 + h * 8192 + kg * 2048;
                w2h[kg] = *(const bfrag*)(wb + lane * 16);
                w2l[kg] = *(const bfrag*)(wb + 1024 + lane * 16);
            }
            float bv = b2[h * 16 + n];
            f4 ca = {bv, bv, bv, bv};
            f4 cb = {bv, bv, bv, bv};
#pragma unroll
            for (int pp = 0; pp < 2; ++pp) {
#pragma unroll
                for (int kg = 0; kg < 4; ++kg) {
                    const char* xv = xlds + 2 * 16384 + pp * 8192 + kg * 2048 + lane * 16;
                    bfrag ah = *(const bfrag*)xv, al = *(const bfrag*)(xv + 1024);
                    if (pp == 0) {
                        ca = mfma_bf16(ah, w2h[kg], ca);
                        ca = mfma_bf16(al, w2h[kg], ca);
                        ca = mfma_bf16(ah, w2l[kg], ca);
                    } else {
                        cb = mfma_bf16(ah, w2h[kg], cb);
                        cb = mfma_bf16(al, w2h[kg], cb);
                        cb = mfma_bf16(ah, w2l[kg], cb);
                    }
                }
            }
            store_rne2(ca, cb,
                       kv + (size_t)bh * 196608 + (size_t)(s32 >> 2) * 12288
                       + 8192 + (s32 & 3) * 1024, lane);
        }
    }
}

// ---------- fused flash attention ----------
// Block = 2 waves x 32 q-rows; grid (32, 32 bh) = 1024 blocks -> 6 blocks/CU
// (LDS-limited), 3 waves/SIMD. Per 128-key chunk: stage 12KB double-buffered
// (explicit vmcnt(0) drain before barrier — correctness-critical, R3/R4).
// Per 32-key sub: S^T = k'(A) x q'hi/lo(B); exp2; pf = DIRECT reg pack
// (sigma/tau cancellation — no cross-lane); PV: o = mfma(vt, pf) giving
// C[m=dim][n=qrow]; l via ones-MFMA. Epilogue: x written as bf16 A-frags
// (pi layout) for k_out.
__global__ __launch_bounds__(128) void k_attn(
    const char* __restrict__ qb, const char* __restrict__ kvg,
    char* __restrict__ xb)
{
    __shared__ __align__(16) char kbuf[2][12288];
    const int tid = threadIdx.x;
    const int w = tid >> 6, lane = tid & 63;
    const int bh = blockIdx.y;
    const int q0 = blockIdx.x * 64 + w * 32;

    const char* qpb = qb + (size_t)bh * 262144 + (size_t)(q0 >> 4) * 2048;
    bfrag qh0 = *(const bfrag*)(qpb + lane * 16);
    bfrag ql0 = *(const bfrag*)(qpb + 1024 + lane * 16);
    bfrag qh1 = *(const bfrag*)(qpb + 2048 + lane * 16);
    bfrag ql1 = *(const bfrag*)(qpb + 3072 + lane * 16);

    const char* kvb = kvg + (size_t)bh * 196608;

    union { unsigned u[4]; bfrag v; } onesu;
    onesu.u[0] = 0x3F803F80u; onesu.u[1] = 0x3F803F80u;
    onesu.u[2] = 0x3F803F80u; onesu.u[3] = 0x3F803F80u;
    const bfrag ones = onesu.v;

    f4 o0 = {0.f, 0.f, 0.f, 0.f}, o1 = {0.f, 0.f, 0.f, 0.f};
    f4 l0 = {0.f, 0.f, 0.f, 0.f}, l1 = {0.f, 0.f, 0.f, 0.f};

    auto stage = [&](char* db, const char* gsrc) {
#pragma unroll
        for (int i = 0; i < 6; ++i)
            stage16(db + (w * 6 + i) * 1024, gsrc + (w * 6 + i) * 1024 + lane * 16);
    };

    stage(kbuf[0], kvb);
    const char* gnext = kvb + 12288;
    int cur = 0;
    for (int ch = 0; ch < 16; ++ch) {
        asm volatile("s_waitcnt vmcnt(0)" ::: "memory");
        __syncthreads();
        if (ch < 15) { stage(kbuf[cur ^ 1], gnext); gnext += 12288; }
        const char* kb = kbuf[cur];
#pragma unroll
        for (int sub = 0; sub < 4; ++sub) {
            bfrag ka = *(const bfrag*)(kb + (2 * sub) * 1024 + lane * 16);
            bfrag kc2 = *(const bfrag*)(kb + (2 * sub + 1) * 1024 + lane * 16);
            bfrag vf = *(const bfrag*)(kb + 8192 + sub * 1024 + lane * 16);
            {   // q-frag 0
                f4 sa = {0.f, 0.f, 0.f, 0.f}, sb = {0.f, 0.f, 0.f, 0.f};
                sa = mfma_bf16(ka, qh0, sa);  sa = mfma_bf16(ka, ql0, sa);
                sb = mfma_bf16(kc2, qh0, sb); sb = mfma_bf16(kc2, ql0, sb);
                union { unsigned u[4]; bfrag v; } pf;
                pf.u[0] = pk_trunc(fexp2(sa[0]), fexp2(sa[1]));
                pf.u[1] = pk_trunc(fexp2(sa[2]), fexp2(sa[3]));
                pf.u[2] = pk_trunc(fexp2(sb[0]), fexp2(sb[1]));
                pf.u[3] = pk_trunc(fexp2(sb[2]), fexp2(sb[3]));
                o0 = mfma_bf16(vf, pf.v, o0);
                l0 = mfma_bf16(ones, pf.v, l0);
            }
            {   // q-frag 1
                f4 sa = {0.f, 0.f, 0.f, 0.f}, sb = {0.f, 0.f, 0.f, 0.f};
                sa = mfma_bf16(ka, qh1, sa);  sa = mfma_bf16(ka, ql1, sa);
                sb = mfma_bf16(kc2, qh1, sb); sb = mfma_bf16(kc2, ql1, sb);
                union { unsigned u[4]; bfrag v; } pf;
                pf.u[0] = pk_trunc(fexp2(sa[0]), fexp2(sa[1]));
                pf.u[1] = pk_trunc(fexp2(sa[2]), fexp2(sa[3]));
                pf.u[2] = pk_trunc(fexp2(sb[0]), fexp2(sb[1]));
                pf.u[3] = pk_trunc(fexp2(sb[2]), fexp2(sb[3]));
                o1 = mfma_bf16(vf, pf.v, o1);
                l1 = mfma_bf16(ones, pf.v, l1);
            }
        }
        cur ^= 1;
    }

    // epilogue: o C[m=dim 4qd+r][n=qrow lane&15]; x-frag write (pi layout):
    // [panel][kg = h>>1][lane][ (h&1)*8 + 2B*r ]
    const int bbk = bh >> 3, h = bh & 7;
    const int gp0 = bbk * 128 + (q0 >> 4);
    char* xw = xb + (size_t)gp0 * 4096 + (h >> 1) * 1024 + lane * 16 + (h & 1) * 8;
    float inv0 = 1.0f / l0[0];
    float inv1 = 1.0f / l1[0];
    u2 s0 = {pk_rne(o0[0] * inv0, o0[1] * inv0), pk_rne(o0[2] * inv0, o0[3] * inv0)};
    u2 s1 = {pk_rne(o1[0] * inv1, o1[1] * inv1), pk_rne(o1[2] * inv1, o1[3] * inv1)};
    *(u2*)xw = s0;
    *(u2*)(xw + 4096) = s1;
}

// ---------- output projection (MFMA) ----------
// 256 blocks x 2 waves; wave-task = one 16-seq panel x 128 outcols.
// A = x-frags loaded directly (pi layout), B = Wo image img4 (pi-matched).
__global__ __launch_bounds__(128) void k_out(
    const char* __restrict__ xb, const char* __restrict__ wimg,
    const float* __restrict__ bo, float* __restrict__ out)
{
    const int tid = threadIdx.x;
    const int w = tid >> 6, lane = tid & 63;
    const int n = lane & 15, qd = lane >> 4;
    const int panel = blockIdx.x * 2 + w;
    const int row0 = panel * 16;

    bfrag xf[4];
#pragma unroll
    for (int kg = 0; kg < 4; ++kg)
        xf[kg] = *(const bfrag*)(xb + (size_t)panel * 4096 + kg * 1024 + lane * 16);

#pragma unroll
    for (int t = 0; t < 8; ++t) {
        float bv = bo[t * 16 + n];
        f4 cacc = {bv, bv, bv, bv};
#pragma unroll
        for (int kg = 0; kg < 4; ++kg) {
            const char* wb = wimg + 4 * 65536 + t * 8192 + kg * 2048;
            bfrag wh = *(const bfrag*)(wb + lane * 16);
            bfrag wl = *(const bfrag*)(wb + 1024 + lane * 16);
            cacc = mfma_bf16(xf[kg], wh, cacc);
            cacc = mfma_bf16(xf[kg], wl, cacc);
        }
#pragma unroll
        for (int r = 0; r < 4; ++r)
            out[(size_t)(row0 + qd * 4 + r) * 128 + t * 16 + n] = cacc[r];
    }
}

extern "C" void kernel_launch(void* const* d_in, const int* in_sizes, int n_in,
                              void* d_out, int out_size, void* d_ws, size_t ws_size,
                              hipStream_t stream)
{
    const float* query = (const float*)d_in[0];
    const float* key   = (const float*)d_in[1];
    const float* value = (const float*)d_in[2];
    const float* pos   = (const float*)d_in[3];
    const float* W0 = (const float*)d_in[4];
    const float* b0 = (const float*)d_in[5];
    const float* W1 = (const float*)d_in[6];
    const float* b1 = (const float*)d_in[7];
    const float* W2 = (const float*)d_in[8];
    const float* b2 = (const float*)d_in[9];
    const float* Wo = (const float*)d_in[10];
    const float* bo = (const float*)d_in[11];

    char* ws = (char*)d_ws;
    char* qbuf = ws + WS_QB;
    char* kv   = ws + WS_KV;
    char* xbuf = ws + WS_X;
    char* wimg = ws + WS_WI;
    float* out = (float*)d_out;

    w_prep<<<dim3(40), 256, 0, stream>>>(W0, W1, W2, Wo, wimg);
    k_proj<<<dim3(256), 256, 0, stream>>>(query, key, value, pos, b0, b1, b2,
                                          wimg, qbuf, kv);
    k_attn<<<dim3(32, 32), 128, 0, stream>>>(qbuf, kv, xbuf);
    k_out<<<dim3(256), 128, 0, stream>>>(xbuf, wimg, bo, out);
}